// Round 4
// baseline (51517.004 us; speedup 1.0000x reference)
//
#include <hip/hip_runtime.h>
#include <math.h>
#include <stdint.h>

#define BATCH 512
#define SLEN 256
#define HDIM 256     // hidden per direction
#define NGATE 1024   // 4*HDIM
#define TC 32        // LSTM time-chunk
#define BC 64        // attention batch-chunk

// ---------------------------------------------------------------------------
// fp32 GEMM: C[M,N] = A[M,K] @ W[N,K]^T (+bias) with optional row remap of A
// (rb_shift>=0: logical row r -> physical row (r>>rb)*SLEN + (r&mask), used to
// gather time-chunks out of [B,S,*] activations), optional accumulate into C,
// relu, per-row mask. M,N multiples of 128; K multiple of 4 (guarded for K=4).
// ---------------------------------------------------------------------------
#define TM 128
#define TN 128
#define TKK 16
#define GF_RELU 1
#define GF_ROWMASK 2
#define GF_ACCUM 4

__global__ __launch_bounds__(256) void gemm_kernel(
    const float* __restrict__ A, const float* __restrict__ W,
    const float* __restrict__ bias, const float* __restrict__ rowmask,
    float* __restrict__ C, int M, int N, int K,
    int lda, int ldw, int ldc, int flags, int rb_shift)
{
  __shared__ float As[TKK][TM + 4];
  __shared__ float Ws[TKK][TN + 4];
  const int tid = threadIdx.x;
  const int tx = tid & 15, ty = tid >> 4;
  const int m0 = blockIdx.y * TM;
  const int n0 = blockIdx.x * TN;
  float acc[8][8];
#pragma unroll
  for (int i = 0; i < 8; ++i)
#pragma unroll
    for (int j = 0; j < 8; ++j) acc[i][j] = 0.f;

  for (int k0 = 0; k0 < K; k0 += TKK) {
#pragma unroll
    for (int p = 0; p < 2; ++p) {
      int f4 = p * 256 + tid;
      int row = f4 >> 2;
      int kk = (f4 & 3) * 4;
      float4 va = make_float4(0.f, 0.f, 0.f, 0.f);
      float4 vw = make_float4(0.f, 0.f, 0.f, 0.f);
      if (k0 + kk < K) {  // K is a multiple of 4 in all uses
        int r = m0 + row;
        int pr = (rb_shift >= 0)
                     ? ((r >> rb_shift) * SLEN + (r & ((1 << rb_shift) - 1)))
                     : r;
        va = *(const float4*)(A + (size_t)pr * lda + k0 + kk);
        vw = *(const float4*)(W + (size_t)(n0 + row) * ldw + k0 + kk);
      }
      As[kk + 0][row] = va.x; As[kk + 1][row] = va.y;
      As[kk + 2][row] = va.z; As[kk + 3][row] = va.w;
      Ws[kk + 0][row] = vw.x; Ws[kk + 1][row] = vw.y;
      Ws[kk + 2][row] = vw.z; Ws[kk + 3][row] = vw.w;
    }
    __syncthreads();
#pragma unroll
    for (int kk = 0; kk < TKK; ++kk) {
      float a[8], w[8];
      float4 t0 = *(const float4*)&As[kk][ty * 8];
      float4 t1 = *(const float4*)&As[kk][ty * 8 + 4];
      a[0]=t0.x; a[1]=t0.y; a[2]=t0.z; a[3]=t0.w;
      a[4]=t1.x; a[5]=t1.y; a[6]=t1.z; a[7]=t1.w;
      float4 s0 = *(const float4*)&Ws[kk][tx * 8];
      float4 s1 = *(const float4*)&Ws[kk][tx * 8 + 4];
      w[0]=s0.x; w[1]=s0.y; w[2]=s0.z; w[3]=s0.w;
      w[4]=s1.x; w[5]=s1.y; w[6]=s1.z; w[7]=s1.w;
#pragma unroll
      for (int i = 0; i < 8; ++i)
#pragma unroll
        for (int j = 0; j < 8; ++j) acc[i][j] += a[i] * w[j];
    }
    __syncthreads();
  }
  float bv[8];
#pragma unroll
  for (int j = 0; j < 8; ++j) bv[j] = bias ? bias[n0 + tx * 8 + j] : 0.f;
#pragma unroll
  for (int i = 0; i < 8; ++i) {
    int m = m0 + ty * 8 + i;
    float rm = (flags & GF_ROWMASK) ? rowmask[m] : 1.f;
    float* cp = C + (size_t)m * ldc + n0 + tx * 8;
    float o[8];
#pragma unroll
    for (int j = 0; j < 8; ++j) {
      float v = acc[i][j] + bv[j];
      if (flags & GF_ACCUM) v += cp[j];
      if (flags & GF_RELU) v = fmaxf(v, 0.f);
      o[j] = v * rm;
    }
    *(float4*)cp = make_float4(o[0], o[1], o[2], o[3]);
    *(float4*)(cp + 4) = make_float4(o[4], o[5], o[6], o[7]);
  }
}

// ---------------------------------------------------------------------------
// BiLSTM chunk kernel. grid = 128 (dir = bx>>6, 8 batches = bx&63), 1024 thr.
// thread = (u = tid>>2, ksub = tid&3 -> k-quarter). Partial dots for gate rows
// {u,u+256,u+512,u+768} over 64 k's x 8 batches; shfl_xor(1,2) completes;
// lane updates 2 batches (g = ksub*2+{0,1}) of unit u. h in LDS, c in regs;
// both persisted to h_g/c_g between chunk launches. Outputs split into
// yf (dir0) / yb (dir1), each [B,S,256].
// Chunked xW layout [b][tt][2048] (tt in increasing t): stride_t=2048,
// stride_b=TC*2048; bw reads row (nsteps-1-s). Decoder L0: stride_t=0.
// ---------------------------------------------------------------------------
__global__ __launch_bounds__(1024) void lstm_kernel(
    const float* __restrict__ xw, const float* __restrict__ whh,
    const float* __restrict__ mask, float* __restrict__ yf,
    float* __restrict__ yb, float* __restrict__ h_g, float* __restrict__ c_g,
    int t0, int nsteps, int first, int xw_stride_t, int xw_stride_b)
{
  __shared__ float h_s[8][HDIM];
  const int tid = threadIdx.x;
  const int u = tid >> 2;
  const int ksub = tid & 3;
  const int k0 = ksub * 64;
  const int dir = blockIdx.x >> 6;
  const int b0 = (blockIdx.x & 63) * 8;
  const size_t stbase = (size_t)dir * BATCH * HDIM;

  if (first) {
    for (int i = tid; i < 8 * HDIM; i += 1024) ((float*)h_s)[i] = 0.f;
  } else {
    for (int i = tid; i < 8 * HDIM; i += 1024) {
      int g = i >> 8, ii = i & 255;
      h_s[g][ii] = h_g[stbase + (size_t)(b0 + g) * HDIM + ii];
    }
  }
  const int g_a = ksub * 2, g_b = ksub * 2 + 1;
  float c0 = 0.f, c1 = 0.f;
  if (!first) {
    c0 = c_g[stbase + (size_t)(b0 + g_a) * HDIM + u];
    c1 = c_g[stbase + (size_t)(b0 + g_b) * HDIM + u];
  }
  __syncthreads();

  const float* w0 = whh + ((size_t)dir * NGATE + u) * HDIM + k0;
  const float* w1 = w0 + 256 * HDIM;
  const float* w2 = w0 + 512 * HDIM;
  const float* w3 = w0 + 768 * HDIM;
  float* yd = dir ? yb : yf;

  for (int s = 0; s < nsteps; ++s) {
    const int t = dir ? (SLEN - 1 - (t0 + s)) : (t0 + s);
    const int xrow = dir ? (nsteps - 1 - s) : s;
    float acc[4][8];
#pragma unroll
    for (int r = 0; r < 4; ++r)
#pragma unroll
      for (int g = 0; g < 8; ++g) acc[r][g] = 0.f;

#pragma unroll 2
    for (int kq = 0; kq < 16; ++kq) {
      float4 a0 = *(const float4*)(w0 + kq * 4);
      float4 a1 = *(const float4*)(w1 + kq * 4);
      float4 a2 = *(const float4*)(w2 + kq * 4);
      float4 a3 = *(const float4*)(w3 + kq * 4);
#pragma unroll
      for (int g = 0; g < 8; ++g) {
        float4 hv = *(const float4*)(&h_s[g][k0 + kq * 4]);
        acc[0][g] += a0.x*hv.x + a0.y*hv.y + a0.z*hv.z + a0.w*hv.w;
        acc[1][g] += a1.x*hv.x + a1.y*hv.y + a1.z*hv.z + a1.w*hv.w;
        acc[2][g] += a2.x*hv.x + a2.y*hv.y + a2.z*hv.z + a2.w*hv.w;
        acc[3][g] += a3.x*hv.x + a3.y*hv.y + a3.z*hv.z + a3.w*hv.w;
      }
    }
#pragma unroll
    for (int r = 0; r < 4; ++r)
#pragma unroll
      for (int g = 0; g < 8; ++g) {
        float v = acc[r][g];
        v += __shfl_xor(v, 1);
        v += __shfl_xor(v, 2);
        acc[r][g] = v;
      }
    __syncthreads();  // all reads of old h done

#pragma unroll
    for (int j = 0; j < 2; ++j) {
      int g = j ? g_b : g_a;
      float cc = j ? c1 : c0;
      int b = b0 + g;
      const float* xwp = xw + (size_t)b * xw_stride_b +
                         (size_t)xrow * xw_stride_t + dir * NGATE;
      float gi = acc[0][g] + xwp[u];
      float gf = acc[1][g] + xwp[u + 256];
      float gg = acc[2][g] + xwp[u + 512];
      float go = acc[3][g] + xwp[u + 768];
      float mt = mask[(size_t)b * SLEN + t];
      float si = 1.f / (1.f + expf(-gi));
      float sf = 1.f / (1.f + expf(-gf));
      float so = 1.f / (1.f + expf(-go));
      float cn = sf * cc + si * tanhf(gg);
      float hn = so * tanhf(cn);
      float hp = h_s[g][u];
      float hnew = mt * hn + (1.f - mt) * hp;
      cc = mt * cn + (1.f - mt) * cc;
      if (j) c1 = cc; else c0 = cc;
      h_s[g][u] = hnew;
      yd[((size_t)b * SLEN + t) * HDIM + u] = hnew * mt;
    }
    __syncthreads();
  }

  for (int i = tid; i < 8 * HDIM; i += 1024) {
    int g = i >> 8, ii = i & 255;
    h_g[stbase + (size_t)(b0 + g) * HDIM + ii] = h_s[g][ii];
  }
  c_g[stbase + (size_t)(b0 + g_a) * HDIM + u] = c0;
  c_g[stbase + (size_t)(b0 + g_b) * HDIM + u] = c1;
}

// ---------------------------------------------------------------------------
// Encoder MHA over a batch chunk. block=(head, bb); thread = one q row.
// Keys processed in two 128-key halves through 32 KB LDS; online softmax.
// ctx split: heads 0-3 -> ctxf cols h*64, heads 4-7 -> ctxb cols (h-4)*64.
// ---------------------------------------------------------------------------
__global__ __launch_bounds__(256) void attn_kernel(
    const float* __restrict__ qkv,   // [BC,S,1536] chunk
    const float* __restrict__ mask,  // [B,S] global
    float* __restrict__ ctxf, float* __restrict__ ctxb, int b0)
{
  __shared__ float Ks[128][64];
  const int h = blockIdx.x;
  const int bb = blockIdx.y;
  const int b = b0 + bb;
  const int tid = threadIdx.x;
  const float* base = qkv + (size_t)bb * SLEN * 1536;

  float4 q[16], o[16];
  const float* qp = base + (size_t)tid * 1536 + h * 64;
#pragma unroll
  for (int i = 0; i < 16; ++i) {
    q[i] = *(const float4*)(qp + i * 4);
    o[i] = make_float4(0.f, 0.f, 0.f, 0.f);
  }
  float m = -1e30f, l = 0.f;
  for (int half = 0; half < 2; ++half) {
    __syncthreads();
    for (int i = tid; i < 128 * 16; i += 256) {
      int krow = i >> 4, dq = i & 15;
      *(float4*)&Ks[krow][dq * 4] = *(const float4*)(
          base + (size_t)(half * 128 + krow) * 1536 + 512 + h * 64 + dq * 4);
    }
    __syncthreads();
    for (int k2 = 0; k2 < 128; ++k2) {
      int k = half * 128 + k2;
      float mk = mask[(size_t)b * SLEN + k];
      if (mk > 0.f) {
        float s = 0.f;
#pragma unroll
        for (int i = 0; i < 16; ++i) {
          float4 kv = *(const float4*)&Ks[k2][i * 4];
          s += q[i].x*kv.x + q[i].y*kv.y + q[i].z*kv.z + q[i].w*kv.w;
        }
        s *= 0.125f;
        if (s > m) {
          float corr = expf(m - s);
          l *= corr;
#pragma unroll
          for (int i = 0; i < 16; ++i) {
            o[i].x *= corr; o[i].y *= corr; o[i].z *= corr; o[i].w *= corr;
          }
          m = s;
        }
        float p = expf(s - m);
        l += p;
        const float* vp = base + (size_t)k * 1536 + 1024 + h * 64;
#pragma unroll
        for (int i = 0; i < 16; ++i) {
          float4 vv = *(const float4*)(vp + i * 4);
          o[i].x += p*vv.x; o[i].y += p*vv.y; o[i].z += p*vv.z; o[i].w += p*vv.w;
        }
      }
    }
  }
  float inv = 1.f / l;
  float* op = (h < 4 ? ctxf : ctxb) + ((size_t)b * SLEN + tid) * 256 + (h & 3) * 64;
#pragma unroll
  for (int i = 0; i < 16; ++i)
    *(float4*)(op + i * 4) = make_float4(o[i].x*inv, o[i].y*inv, o[i].z*inv, o[i].w*inv);
}

// ---------------------------------------------------------------------------
// Small kernels
// ---------------------------------------------------------------------------
__global__ __launch_bounds__(256) void embed_kernel(
    const float* __restrict__ src, const float* __restrict__ ew,
    const float* __restrict__ eb, float* __restrict__ out)
{
  size_t row = blockIdx.x;
  int i = threadIdx.x;
  out[row * 256 + i] = src[row] * ew[i] + eb[i];
}

__device__ __forceinline__ float breduce_sum(float v, float* sh) {
  int tid = threadIdx.x;
  sh[tid] = v; __syncthreads();
  for (int s = 128; s > 0; s >>= 1) {
    if (tid < s) sh[tid] += sh[tid + s];
    __syncthreads();
  }
  float r = sh[0]; __syncthreads();
  return r;
}

__global__ __launch_bounds__(256) void stats_kernel(
    const float* __restrict__ src, const float* __restrict__ mask,
    float* __restrict__ stats4)
{
  __shared__ float sh[256];
  const int b = blockIdx.x, t = threadIdx.x;
  const float m = mask[b * 256 + t];
  const float x = src[b * 256 + t] * m;
  float sum = breduce_sum(x, sh);
  float mean = sum * (1.f / 256.f);
  float d = x - mean;
  float var = breduce_sum(d * d, sh) / 255.f;
  float sd = fmaxf(sqrtf(var), 1e-6f);
  float denom = fmaxf(breduce_sum(m, sh), 1e-6f);
  float pk = breduce_sum((x > 1.f + 2.f * sd) ? 1.f : 0.f, sh) / denom;
  float e1 = x - 1.f;
  float sk = (breduce_sum(e1 * e1 * e1 * m, sh) * (1.f / 256.f)) / (sd * sd * sd + 1e-6f);
  float etot = 0.f;
  for (int f = 0; f < 5; ++f) {
    double ang = -2.0 * 3.14159265358979323846 * (double)(f * t) / 256.0;
    float re = breduce_sum(x * (float)cos(ang), sh);
    float im = breduce_sum(x * (float)sin(ang), sh);
    etot += sqrtf(re * re + im * im);
  }
  if (t == 0) {
    stats4[b * 4 + 0] = sd;
    stats4[b * 4 + 1] = pk;
    stats4[b * 4 + 2] = sk;
    stats4[b * 4 + 3] = etot / 5.f;
  }
}

__global__ __launch_bounds__(256) void zmeanmax_kernel(
    const float* __restrict__ z_e, const float* __restrict__ mask,
    float* __restrict__ pooled)
{
  const int b = blockIdx.x, e = threadIdx.x;
  float acc = 0.f, mx = -INFINITY, dsum = 0.f;
  const float* zp = z_e + (size_t)b * SLEN * 256 + e;
  const float* mp = mask + (size_t)b * SLEN;
  for (int t = 0; t < SLEN; ++t) {
    float mt = mp[t];
    float v = zp[(size_t)t * 256] * mt;
    acc += v; mx = fmaxf(mx, v); dsum += mt;
  }
  float denom = fmaxf(dsum, 1e-6f);
  pooled[(size_t)b * 768 + e] = acc / denom;
  pooled[(size_t)b * 768 + 256 + e] = mx;
}

__global__ __launch_bounds__(256) void rowsq_kernel(
    const float* __restrict__ a, float* __restrict__ out)
{
  __shared__ float sh[256];
  const int r = blockIdx.x;
  float v = a[(size_t)r * 256 + threadIdx.x];
  float s = breduce_sum(v * v, sh);
  if (threadIdx.x == 0) out[r] = s;
}

// ---------------------------------------------------------------------------
// JAX threefry2x32 (key=(0,42)), PARTITIONABLE scheme (modern default):
// bits[i] = fold of the two output words of threefry2x32(key, (hi(i), lo(i))).
// For bit_width==32 JAX XOR-folds: bits = b1 ^ b2 (uint64 path packs
// (b1<<32)|b2; the 32-bit path folds instead of truncating).
// ---------------------------------------------------------------------------
__device__ __forceinline__ uint2 threefry2x32(uint32_t k0, uint32_t k1,
                                              uint32_t x0, uint32_t x1) {
  uint32_t k2 = k0 ^ k1 ^ 0x1BD11BDAu;
  x0 += k0; x1 += k1;
#define TFR(r) { x0 += x1; x1 = (x1 << r) | (x1 >> (32 - r)); x1 ^= x0; }
  TFR(13) TFR(15) TFR(26) TFR(6)
  x0 += k1; x1 += k2 + 1u;
  TFR(17) TFR(29) TFR(16) TFR(24)
  x0 += k2; x1 += k0 + 2u;
  TFR(13) TFR(15) TFR(26) TFR(6)
  x0 += k0; x1 += k1 + 3u;
  TFR(17) TFR(29) TFR(16) TFR(24)
  x0 += k1; x1 += k2 + 4u;
  TFR(13) TFR(15) TFR(26) TFR(6)
  x0 += k2; x1 += k0 + 5u;
#undef TFR
  return make_uint2(x0, x1);
}

__global__ __launch_bounds__(256) void sample_kernel(
    const float* __restrict__ dots, const float* __restrict__ p2,
    const float* __restrict__ c2, float* __restrict__ out_idx_f,
    int* __restrict__ idx_i)
{
  const int b = blockIdx.x, tid = threadIdx.x;
  const float p2b = p2[b];
  float best = -INFINITY; int bidx = 0;
  for (int k = tid; k < 16384; k += 256) {
    float d2 = fmaxf(p2b + c2[k] - 2.f * dots[(size_t)b * 16384 + k], 0.f);
    float logit = -sqrtf(d2) / 0.7f;
    uint32_t i = (uint32_t)b * 16384u + (uint32_t)k;
    // partitionable: ctr = (0, i); 32-bit output = XOR-fold of both words
    uint2 r = threefry2x32(0u, 42u, 0u, i);
    uint32_t bits = r.x ^ r.y;
    float u = __uint_as_float((bits >> 9) | 0x3f800000u) - 1.0f;
    u = u + 1.17549435e-38f;
    u = fmaxf(u, 1.17549435e-38f);
    float g = -logf(-logf(u));
    float val = logit + g;
    if (val > best) { best = val; bidx = k; }
  }
  __shared__ float bvs[256];
  __shared__ int bks[256];
  bvs[tid] = best; bks[tid] = bidx;
  __syncthreads();
  for (int s = 128; s > 0; s >>= 1) {
    if (tid < s) {
      if (bvs[tid + s] > bvs[tid] ||
          (bvs[tid + s] == bvs[tid] && bks[tid + s] < bks[tid])) {
        bvs[tid] = bvs[tid + s]; bks[tid] = bks[tid + s];
      }
    }
    __syncthreads();
  }
  if (tid == 0) {
    idx_i[b] = bks[0];
    out_idx_f[b] = (float)bks[0];
  }
}

__global__ __launch_bounds__(256) void zqrow_kernel(
    const float* __restrict__ cb, const int* __restrict__ idx,
    float* __restrict__ zqrow)
{
  const int b = blockIdx.x, e = threadIdx.x;
  zqrow[(size_t)b * 256 + e] = cb[(size_t)idx[b] * 256 + e];
}

__global__ __launch_bounds__(256) void zqbcast_kernel(
    const float* __restrict__ zqrow, float* __restrict__ out)
{
  const size_t row = blockIdx.x;   // b*S + t
  const int e = threadIdx.x;
  out[row * 256 + e] = zqrow[(row >> 8) * 256 + e];
}

__global__ __launch_bounds__(256) void recon_kernel(
    const float* __restrict__ hf, const float* __restrict__ hb,
    const float* __restrict__ ow, const float* __restrict__ ob,
    float* __restrict__ out)
{
  const int row = blockIdx.x * 4 + (threadIdx.x >> 6);
  const int lane = threadIdx.x & 63;
  const float* pf = hf + (size_t)row * 256;
  const float* pb = hb + (size_t)row * 256;
  float s = 0.f;
  for (int i = lane; i < 256; i += 64) s += pf[i] * ow[i] + pb[i] * ow[256 + i];
  for (int off = 32; off > 0; off >>= 1) s += __shfl_down(s, off);
  if (lane == 0) out[row] = s + ob[0];
}

// ---------------------------------------------------------------------------
static inline void gemm(const float* A, const float* W, const float* bias,
                        const float* rowmask, float* C, int M, int N, int K,
                        int lda, int ldw, int ldc, int flags, int rb,
                        hipStream_t s) {
  dim3 g(N / TN, M / TM), b(256);
  hipLaunchKernelGGL(gemm_kernel, g, b, 0, s, A, W, bias, rowmask, C,
                     M, N, K, lda, ldw, ldc, flags, rb);
}

// One chunked BiLSTM layer. inF/inB: [B,S,256] halves (inB null -> single
// 256-wide input). Wih: [2,1024,ldwF]; outputs yf/yb may alias inF/inB
// (in-place safe: chunk j's GEMM reads fw times [32j,32j+32) and bw times
// [224-32j,256-32j), all not yet overwritten by LSTM chunks < j).
static void bilstm_layer(const float* inF, const float* inB,
                         const float* Wih, const float* bg, int ldwF,
                         const float* whh, const float* pmask,
                         float* yf, float* yb, float* chunk,
                         float* h_g, float* c_g, hipStream_t st) {
  const int M = BATCH * TC;  // 16384
  for (int c = 0; c < SLEN / TC; ++c) {
    int t0f = c * TC;
    int t0b = SLEN - (c + 1) * TC;
    for (int dir = 0; dir < 2; ++dir) {
      int t0 = dir ? t0b : t0f;
      const float* Wd = Wih + (size_t)dir * NGATE * ldwF;
      const float* bd = bg + dir * NGATE;
      float* Cd = chunk + dir * NGATE;
      if (inB) {
        gemm(inF + (size_t)t0 * 256, Wd, nullptr, nullptr, Cd,
             M, NGATE, 256, 256, ldwF, 2048, 0, 5, st);
        gemm(inB + (size_t)t0 * 256, Wd + 256, bd, nullptr, Cd,
             M, NGATE, 256, 256, ldwF, 2048, GF_ACCUM, 5, st);
      } else {
        gemm(inF + (size_t)t0 * 256, Wd, bd, nullptr, Cd,
             M, NGATE, 256, 256, ldwF, 2048, 0, 5, st);
      }
    }
    hipLaunchKernelGGL(lstm_kernel, dim3(128), dim3(1024), 0, st,
                       chunk, whh, pmask, yf, yb, h_g, c_g,
                       t0f, TC, (c == 0) ? 1 : 0, 2048, TC * 2048);
  }
}

extern "C" void kernel_launch(void* const* d_in, const int* in_sizes, int n_in,
                              void* d_out, int out_size, void* d_ws, size_t ws_size,
                              hipStream_t stream) {
  (void)in_sizes; (void)n_in; (void)out_size;
  const float* src     = (const float*)d_in[0];
  const float* pmask   = (const float*)d_in[1];
  const float* emb_w   = (const float*)d_in[3];
  const float* emb_b   = (const float*)d_in[4];
  const float* e0_Wih  = (const float*)d_in[5];
  const float* e0_Whh  = (const float*)d_in[6];
  const float* e0_b    = (const float*)d_in[7];
  const float* e1_Wih  = (const float*)d_in[8];
  const float* e1_Whh  = (const float*)d_in[9];
  const float* e1_b    = (const float*)d_in[10];
  const float* a_in_w  = (const float*)d_in[11];
  const float* a_in_b  = (const float*)d_in[12];
  const float* a_out_w = (const float*)d_in[13];
  const float* a_out_b = (const float*)d_in[14];
  const float* fc_w    = (const float*)d_in[15];
  const float* fc_b    = (const float*)d_in[16];
  const float* st_w    = (const float*)d_in[17];
  const float* st_b    = (const float*)d_in[18];
  const float* po_w    = (const float*)d_in[19];
  const float* po_b    = (const float*)d_in[20];
  const float* cb      = (const float*)d_in[21];
  const float* dfc_w   = (const float*)d_in[22];
  const float* dfc_b   = (const float*)d_in[23];
  const float* da_in_w = (const float*)d_in[24];
  const float* da_in_b = (const float*)d_in[25];
  const float* da_out_w= (const float*)d_in[26];
  const float* da_out_b= (const float*)d_in[27];
  const float* d0_Wih  = (const float*)d_in[28];
  const float* d0_Whh  = (const float*)d_in[29];
  const float* d0_b    = (const float*)d_in[30];
  const float* d1_Wih  = (const float*)d_in[31];
  const float* d1_Whh  = (const float*)d_in[32];
  const float* d1_b    = (const float*)d_in[33];
  const float* out_w   = (const float*)d_in[34];
  const float* out_b   = (const float*)d_in[35];

  float* out = (float*)d_out;
  float* ws  = (float*)d_ws;

  // ---- workspace layout: 3 big slots + smalls = ~415 MB ----
  const size_t U = 33554432;             // BATCH*SLEN*256
  float* S1 = ws;                        // [B,S,256]
  float* S2 = ws + U;                    // [B,S,256]
  float* S3 = ws + 2 * U;                // chunk space (<= U)
  float* SM = ws + 3 * U;
  float* h_state = SM;                   // 2*512*256 = 262144
  float* c_state = SM + 262144;          // 262144
  float* pooled  = SM + 524288;          // 512*768
  float* phrase  = SM + 917504;          // 512*256
  float* stats4  = SM + 1048576;         // 512*4
  float* p2      = SM + 1050624;         // 512
  float* c2      = SM + 1051136;         // 16384
  int*   idx_i   = (int*)(SM + 1067520); // 512
  float* zqrow   = SM + 1068032;         // 512*256
  float* hd      = SM + 1199104;         // 512*512
  float* vb      = SM + 1461248;         // 512*512
  float* dab     = SM + 1723392;         // 512*512
  float* xwdec   = SM + 1985536;         // 512*2048
  const size_t NEED_BYTES = (3 * U + 3034112) * sizeof(float);
  if (ws_size < NEED_BYTES) return;  // diagnostic: fail on values, not fault

  float* o_recon = out;                  // 131072
  float* o_ze    = out + 131072;         // B*S*256  (OZ1: also embed/ctxf scratch)
  float* o_zq    = out + 33685504;       // B*S*256  (OZ2: also ctxb scratch)
  float* o_idx   = out + 67239936;       // 512

  const int BS = BATCH * SLEN;

  // ---- encoder ----
  hipLaunchKernelGGL(embed_kernel, dim3(BS), dim3(256), 0, stream,
                     src, emb_w, emb_b, o_ze);
  bilstm_layer(o_ze, nullptr, e0_Wih, e0_b, 256, e0_Whh, pmask,
               S1, S2, S3, h_state, c_state, stream);
  bilstm_layer(S1, S2, e1_Wih, e1_b, 512, e1_Whh, pmask,
               S1, S2, S3, h_state, c_state, stream);   // in-place

  // attention, batch-chunked: QKV into S3, ctx into o_ze/o_zq regions
  for (int b0 = 0; b0 < BATCH; b0 += BC) {
    const float* af = S1 + (size_t)b0 * SLEN * 256;
    const float* ab = S2 + (size_t)b0 * SLEN * 256;
    gemm(af, a_in_w, nullptr, nullptr, S3, BC * SLEN, 1536, 256,
         256, 512, 1536, 0, -1, stream);
    gemm(ab, a_in_w + 256, a_in_b, nullptr, S3, BC * SLEN, 1536, 256,
         256, 512, 1536, GF_ACCUM, -1, stream);
    hipLaunchKernelGGL(attn_kernel, dim3(8, BC), dim3(256), 0, stream,
                       S3, pmask, o_ze, o_zq, b0);
  }
  // attn-out (+row mask) then z_e, batch-chunked through S3
  for (int b0 = 0; b0 < BATCH; b0 += BC) {
    const float* cf = o_ze + (size_t)b0 * SLEN * 256;
    const float* cbk = o_zq + (size_t)b0 * SLEN * 256;
    gemm(cf, a_out_w, nullptr, nullptr, S3, BC * SLEN, 512, 256,
         256, 512, 512, 0, -1, stream);
    gemm(cbk, a_out_w + 256, a_out_b, pmask + (size_t)b0 * SLEN, S3,
         BC * SLEN, 512, 256, 256, 512, 512, GF_ACCUM | GF_ROWMASK, -1, stream);
    gemm(S3, fc_w, fc_b, nullptr, o_ze + (size_t)b0 * SLEN * 256,
         BC * SLEN, 256, 512, 512, 512, 256, 0, -1, stream);
  }

  // ---- pooling / stats / phrase ----
  hipLaunchKernelGGL(zmeanmax_kernel, dim3(512), dim3(256), 0, stream,
                     o_ze, pmask, pooled);
  hipLaunchKernelGGL(stats_kernel, dim3(512), dim3(256), 0, stream,
                     src, pmask, stats4);
  gemm(stats4, st_w, st_b, nullptr, pooled + 512, 512, 256, 4,
       4, 4, 768, 0, -1, stream);
  gemm(pooled, po_w, po_b, nullptr, phrase, 512, 256, 768,
       768, 768, 256, 0, -1, stream);

  // ---- VQ: distances + exact JAX categorical sampling ----
  hipLaunchKernelGGL(rowsq_kernel, dim3(512), dim3(256), 0, stream, phrase, p2);
  hipLaunchKernelGGL(rowsq_kernel, dim3(16384), dim3(256), 0, stream, cb, c2);
  gemm(phrase, cb, nullptr, nullptr, S3, 512, 16384, 256,
       256, 256, 16384, 0, -1, stream);
  hipLaunchKernelGGL(sample_kernel, dim3(512), dim3(256), 0, stream,
                     S3, p2, c2, o_idx, idx_i);
  hipLaunchKernelGGL(zqrow_kernel, dim3(512), dim3(256), 0, stream,
                     cb, idx_i, zqrow);
  hipLaunchKernelGGL(zqbcast_kernel, dim3(BS), dim3(256), 0, stream,
                     zqrow, o_zq);

  // ---- decoder prelude: fc -> (collapsed) MHA -> per-batch constant xW ----
  // z_q constant over t => decoder attention output == its V projection.
  gemm(zqrow, dfc_w, dfc_b, nullptr, hd, 512, 512, 256,
       256, 256, 512, GF_RELU, -1, stream);
  gemm(hd, da_in_w + (size_t)1024 * 512, da_in_b + 1024, nullptr, vb,
       512, 512, 512, 512, 512, 512, 0, -1, stream);
  gemm(vb, da_out_w, da_out_b, nullptr, dab, 512, 512, 512,
       512, 512, 512, 0, -1, stream);
  gemm(dab, d0_Wih, d0_b, nullptr, xwdec, 512, 2048, 512,
       512, 512, 2048, 0, -1, stream);

  // ---- decoder LSTMs + output projection ----
  hipLaunchKernelGGL(lstm_kernel, dim3(128), dim3(1024), 0, stream,
                     xwdec, d0_Whh, pmask, S1, S2, h_state, c_state,
                     0, SLEN, 1, 0, 2048);
  bilstm_layer(S1, S2, d1_Wih, d1_b, 512, d1_Whh, pmask,
               S1, S2, S3, h_state, c_state, stream);   // in-place
  hipLaunchKernelGGL(recon_kernel, dim3(BS / 4), dim3(256), 0, stream,
                     S1, S2, out_w, out_b, o_recon);
}

// Round 6
// 43055.060 us; speedup vs baseline: 1.1965x; 1.1965x over previous
//
#include <hip/hip_runtime.h>
#include <hip/hip_bf16.h>
#include <math.h>
#include <stdint.h>

#define BATCH 512
#define SLEN 256
#define HDIM 256     // hidden per direction
#define NGATE 1024   // 4*HDIM
#define TC 32        // LSTM time-chunk
#define BC 64        // attention batch-chunk

typedef __hip_bfloat16 bf16;
typedef __attribute__((ext_vector_type(8))) short short8;   // 8 bf16 = 4 VGPRs
typedef __attribute__((ext_vector_type(4))) float f32x4;

#define GF_RELU 1
#define GF_ROWMASK 2
#define GF_ACCUM 4

// ---------------------------------------------------------------------------
// bf16 MFMA GEMM: C[M,N] = concatK(A0,A1)[M,K] @ W[N,K]^T (+bias fp32).
// A0 covers k<kHalf, A1 covers k>=kHalf (A1 null -> kHalf=K). Row remap
// rb_shift>=0: logical row r -> (r>>rb)*SLEN + (r&mask) (time-chunk gather).
// Output: fp32 (Cf) or bf16 (Cb). 128x128 tile, BK=32, 4 waves (2x2 of 64x64),
// mfma_f32_16x16x32_bf16. M,N mult of 128; K mult of 32.
// ---------------------------------------------------------------------------
__global__ __launch_bounds__(256) void gemm_bf16_kernel(
    const bf16* __restrict__ A0, const bf16* __restrict__ A1,
    const bf16* __restrict__ W, const float* __restrict__ bias,
    const float* __restrict__ rowmask, float* __restrict__ Cf,
    bf16* __restrict__ Cb, int M, int N, int K, int lda, int ldc,
    int flags, int rb_shift, int kHalf)
{
  __shared__ short As[128][40];   // 32 k + 8 pad
  __shared__ short Bs[128][40];
  const int tid = threadIdx.x;
  const int m0 = blockIdx.y * 128, n0 = blockIdx.x * 128;
  const int wave = tid >> 6, lane = tid & 63;
  const int wm = (wave & 1) * 64, wn = (wave >> 1) * 64;
  const int fm = lane & 15, fq = (lane >> 4) * 8;

  f32x4 acc[4][4];
#pragma unroll
  for (int i = 0; i < 4; ++i)
#pragma unroll
    for (int j = 0; j < 4; ++j) acc[i][j] = (f32x4){0.f, 0.f, 0.f, 0.f};

  for (int k0 = 0; k0 < K; k0 += 32) {
    const bf16* Asrc = (A1 && k0 >= kHalf) ? A1 : A0;
    const int kk = (A1 && k0 >= kHalf) ? (k0 - kHalf) : k0;
#pragma unroll
    for (int p = 0; p < 2; ++p) {
      int idx = p * 256 + tid;          // 512 chunks of 16B
      int r = idx >> 2, q = idx & 3;
      int rl = m0 + r;
      int pr = (rb_shift >= 0)
                   ? ((rl >> rb_shift) * SLEN + (rl & ((1 << rb_shift) - 1)))
                   : rl;
      *(uint4*)&As[r][q * 8] =
          *(const uint4*)(Asrc + (size_t)pr * lda + kk + q * 8);
      *(uint4*)&Bs[r][q * 8] =
          *(const uint4*)(W + (size_t)(n0 + r) * K + k0 + q * 8);
    }
    __syncthreads();
    short8 af[4], bfr[4];
#pragma unroll
    for (int mi = 0; mi < 4; ++mi)
      af[mi] = *(short8*)&As[wm + mi * 16 + fm][fq];
#pragma unroll
    for (int ni = 0; ni < 4; ++ni)
      bfr[ni] = *(short8*)&Bs[wn + ni * 16 + fm][fq];
#pragma unroll
    for (int mi = 0; mi < 4; ++mi)
#pragma unroll
      for (int ni = 0; ni < 4; ++ni)
        acc[mi][ni] = __builtin_amdgcn_mfma_f32_16x16x32_bf16(
            af[mi], bfr[ni], acc[mi][ni], 0, 0, 0);
    __syncthreads();
  }

  const int cr = (lane >> 4) * 4, cc = lane & 15;
#pragma unroll
  for (int mi = 0; mi < 4; ++mi) {
#pragma unroll
    for (int r = 0; r < 4; ++r) {
      int m = m0 + wm + mi * 16 + cr + r;
      float rm = (flags & GF_ROWMASK) ? rowmask[m] : 1.f;
#pragma unroll
      for (int ni = 0; ni < 4; ++ni) {
        int n = n0 + wn + ni * 16 + cc;
        float v = acc[mi][ni][r] + (bias ? bias[n] : 0.f);
        if (flags & GF_RELU) v = fmaxf(v, 0.f);
        v *= rm;
        if (Cb) Cb[(size_t)m * ldc + n] = __float2bfloat16(v);
        else    Cf[(size_t)m * ldc + n] = v;
      }
    }
  }
}

// ---------------------------------------------------------------------------
// fp32 naive GEMM (small ops only: stats K=4, pool, VQ dots, decoder prelude)
// ---------------------------------------------------------------------------
#define TM 128
#define TN 128
#define TKK 16

__global__ __launch_bounds__(256) void gemm_kernel(
    const float* __restrict__ A, const float* __restrict__ W,
    const float* __restrict__ bias, const float* __restrict__ rowmask,
    float* __restrict__ C, int M, int N, int K,
    int lda, int ldw, int ldc, int flags)
{
  __shared__ float As[TKK][TM + 4];
  __shared__ float Ws[TKK][TN + 4];
  const int tid = threadIdx.x;
  const int tx = tid & 15, ty = tid >> 4;
  const int m0 = blockIdx.y * TM;
  const int n0 = blockIdx.x * TN;
  float acc[8][8];
#pragma unroll
  for (int i = 0; i < 8; ++i)
#pragma unroll
    for (int j = 0; j < 8; ++j) acc[i][j] = 0.f;

  for (int k0 = 0; k0 < K; k0 += TKK) {
#pragma unroll
    for (int p = 0; p < 2; ++p) {
      int f4 = p * 256 + tid;
      int row = f4 >> 2;
      int kk = (f4 & 3) * 4;
      float4 va = make_float4(0.f, 0.f, 0.f, 0.f);
      float4 vw = make_float4(0.f, 0.f, 0.f, 0.f);
      if (k0 + kk < K) {
        va = *(const float4*)(A + (size_t)(m0 + row) * lda + k0 + kk);
        vw = *(const float4*)(W + (size_t)(n0 + row) * ldw + k0 + kk);
      }
      As[kk + 0][row] = va.x; As[kk + 1][row] = va.y;
      As[kk + 2][row] = va.z; As[kk + 3][row] = va.w;
      Ws[kk + 0][row] = vw.x; Ws[kk + 1][row] = vw.y;
      Ws[kk + 2][row] = vw.z; Ws[kk + 3][row] = vw.w;
    }
    __syncthreads();
#pragma unroll
    for (int kk = 0; kk < TKK; ++kk) {
      float a[8], w[8];
      float4 t0 = *(const float4*)&As[kk][ty * 8];
      float4 t1 = *(const float4*)&As[kk][ty * 8 + 4];
      a[0]=t0.x; a[1]=t0.y; a[2]=t0.z; a[3]=t0.w;
      a[4]=t1.x; a[5]=t1.y; a[6]=t1.z; a[7]=t1.w;
      float4 s0 = *(const float4*)&Ws[kk][tx * 8];
      float4 s1 = *(const float4*)&Ws[kk][tx * 8 + 4];
      w[0]=s0.x; w[1]=s0.y; w[2]=s0.z; w[3]=s0.w;
      w[4]=s1.x; w[5]=s1.y; w[6]=s1.z; w[7]=s1.w;
#pragma unroll
      for (int i = 0; i < 8; ++i)
#pragma unroll
        for (int j = 0; j < 8; ++j) acc[i][j] += a[i] * w[j];
    }
    __syncthreads();
  }
  float bv[8];
#pragma unroll
  for (int j = 0; j < 8; ++j) bv[j] = bias ? bias[n0 + tx * 8 + j] : 0.f;
#pragma unroll
  for (int i = 0; i < 8; ++i) {
    int m = m0 + ty * 8 + i;
    float rm = (flags & GF_ROWMASK) ? rowmask[m] : 1.f;
    float* cp = C + (size_t)m * ldc + n0 + tx * 8;
    float o[8];
#pragma unroll
    for (int j = 0; j < 8; ++j) {
      float v = acc[i][j] + bv[j];
      if (flags & GF_ACCUM) v += cp[j];
      if (flags & GF_RELU) v = fmaxf(v, 0.f);
      o[j] = v * rm;
    }
    *(float4*)cp = make_float4(o[0], o[1], o[2], o[3]);
    *(float4*)(cp + 4) = make_float4(o[4], o[5], o[6], o[7]);
  }
}

// ---------------------------------------------------------------------------
// BiLSTM chunk kernel (fp32 recurrence, bf16 y output).
// ---------------------------------------------------------------------------
__global__ __launch_bounds__(1024) void lstm_kernel(
    const float* __restrict__ xw, const float* __restrict__ whh,
    const float* __restrict__ mask, bf16* __restrict__ yf,
    bf16* __restrict__ yb, float* __restrict__ h_g, float* __restrict__ c_g,
    int t0, int nsteps, int first, int xw_stride_t, int xw_stride_b)
{
  __shared__ float h_s[8][HDIM];
  const int tid = threadIdx.x;
  const int u = tid >> 2;
  const int ksub = tid & 3;
  const int k0 = ksub * 64;
  const int dir = blockIdx.x >> 6;
  const int b0 = (blockIdx.x & 63) * 8;
  const size_t stbase = (size_t)dir * BATCH * HDIM;

  if (first) {
    for (int i = tid; i < 8 * HDIM; i += 1024) ((float*)h_s)[i] = 0.f;
  } else {
    for (int i = tid; i < 8 * HDIM; i += 1024) {
      int g = i >> 8, ii = i & 255;
      h_s[g][ii] = h_g[stbase + (size_t)(b0 + g) * HDIM + ii];
    }
  }
  const int g_a = ksub * 2, g_b = ksub * 2 + 1;
  float c0 = 0.f, c1 = 0.f;
  if (!first) {
    c0 = c_g[stbase + (size_t)(b0 + g_a) * HDIM + u];
    c1 = c_g[stbase + (size_t)(b0 + g_b) * HDIM + u];
  }
  __syncthreads();

  const float* w0 = whh + ((size_t)dir * NGATE + u) * HDIM + k0;
  const float* w1 = w0 + 256 * HDIM;
  const float* w2 = w0 + 512 * HDIM;
  const float* w3 = w0 + 768 * HDIM;
  bf16* yd = dir ? yb : yf;

  for (int s = 0; s < nsteps; ++s) {
    const int t = dir ? (SLEN - 1 - (t0 + s)) : (t0 + s);
    const int xrow = dir ? (nsteps - 1 - s) : s;
    float acc[4][8];
#pragma unroll
    for (int r = 0; r < 4; ++r)
#pragma unroll
      for (int g = 0; g < 8; ++g) acc[r][g] = 0.f;

#pragma unroll 2
    for (int kq = 0; kq < 16; ++kq) {
      float4 a0 = *(const float4*)(w0 + kq * 4);
      float4 a1 = *(const float4*)(w1 + kq * 4);
      float4 a2 = *(const float4*)(w2 + kq * 4);
      float4 a3 = *(const float4*)(w3 + kq * 4);
#pragma unroll
      for (int g = 0; g < 8; ++g) {
        float4 hv = *(const float4*)(&h_s[g][k0 + kq * 4]);
        acc[0][g] += a0.x*hv.x + a0.y*hv.y + a0.z*hv.z + a0.w*hv.w;
        acc[1][g] += a1.x*hv.x + a1.y*hv.y + a1.z*hv.z + a1.w*hv.w;
        acc[2][g] += a2.x*hv.x + a2.y*hv.y + a2.z*hv.z + a2.w*hv.w;
        acc[3][g] += a3.x*hv.x + a3.y*hv.y + a3.z*hv.z + a3.w*hv.w;
      }
    }
#pragma unroll
    for (int r = 0; r < 4; ++r)
#pragma unroll
      for (int g = 0; g < 8; ++g) {
        float v = acc[r][g];
        v += __shfl_xor(v, 1);
        v += __shfl_xor(v, 2);
        acc[r][g] = v;
      }
    __syncthreads();

#pragma unroll
    for (int j = 0; j < 2; ++j) {
      int g = j ? g_b : g_a;
      float cc = j ? c1 : c0;
      int b = b0 + g;
      const float* xwp = xw + (size_t)b * xw_stride_b +
                         (size_t)xrow * xw_stride_t + dir * NGATE;
      float gi = acc[0][g] + xwp[u];
      float gf = acc[1][g] + xwp[u + 256];
      float gg = acc[2][g] + xwp[u + 512];
      float go = acc[3][g] + xwp[u + 768];
      float mt = mask[(size_t)b * SLEN + t];
      float si = 1.f / (1.f + expf(-gi));
      float sf = 1.f / (1.f + expf(-gf));
      float so = 1.f / (1.f + expf(-go));
      float cn = sf * cc + si * tanhf(gg);
      float hn = so * tanhf(cn);
      float hp = h_s[g][u];
      float hnew = mt * hn + (1.f - mt) * hp;
      cc = mt * cn + (1.f - mt) * cc;
      if (j) c1 = cc; else c0 = cc;
      h_s[g][u] = hnew;
      yd[((size_t)b * SLEN + t) * HDIM + u] = __float2bfloat16(hnew * mt);
    }
    __syncthreads();
  }

  for (int i = tid; i < 8 * HDIM; i += 1024) {
    int g = i >> 8, ii = i & 255;
    h_g[stbase + (size_t)(b0 + g) * HDIM + ii] = h_s[g][ii];
  }
  c_g[stbase + (size_t)(b0 + g_a) * HDIM + u] = c0;
  c_g[stbase + (size_t)(b0 + g_b) * HDIM + u] = c1;
}

// ---------------------------------------------------------------------------
// Encoder MHA over a batch chunk (fp32 QKV in, bf16 ctx out).
// ---------------------------------------------------------------------------
__global__ __launch_bounds__(256) void attn_kernel(
    const float* __restrict__ qkv, const float* __restrict__ mask,
    bf16* __restrict__ ctxf, bf16* __restrict__ ctxb, int b0)
{
  __shared__ float Ks[128][64];
  const int h = blockIdx.x;
  const int bb = blockIdx.y;
  const int b = b0 + bb;
  const int tid = threadIdx.x;
  const float* base = qkv + (size_t)bb * SLEN * 1536;

  float4 q[16], o[16];
  const float* qp = base + (size_t)tid * 1536 + h * 64;
#pragma unroll
  for (int i = 0; i < 16; ++i) {
    q[i] = *(const float4*)(qp + i * 4);
    o[i] = make_float4(0.f, 0.f, 0.f, 0.f);
  }
  float m = -1e30f, l = 0.f;
  for (int half = 0; half < 2; ++half) {
    __syncthreads();
    for (int i = tid; i < 128 * 16; i += 256) {
      int krow = i >> 4, dq = i & 15;
      *(float4*)&Ks[krow][dq * 4] = *(const float4*)(
          base + (size_t)(half * 128 + krow) * 1536 + 512 + h * 64 + dq * 4);
    }
    __syncthreads();
    for (int k2 = 0; k2 < 128; ++k2) {
      int k = half * 128 + k2;
      float mk = mask[(size_t)b * SLEN + k];
      if (mk > 0.f) {
        float s = 0.f;
#pragma unroll
        for (int i = 0; i < 16; ++i) {
          float4 kv = *(const float4*)&Ks[k2][i * 4];
          s += q[i].x*kv.x + q[i].y*kv.y + q[i].z*kv.z + q[i].w*kv.w;
        }
        s *= 0.125f;
        if (s > m) {
          float corr = expf(m - s);
          l *= corr;
#pragma unroll
          for (int i = 0; i < 16; ++i) {
            o[i].x *= corr; o[i].y *= corr; o[i].z *= corr; o[i].w *= corr;
          }
          m = s;
        }
        float p = expf(s - m);
        l += p;
        const float* vp = base + (size_t)k * 1536 + 1024 + h * 64;
#pragma unroll
        for (int i = 0; i < 16; ++i) {
          float4 vv = *(const float4*)(vp + i * 4);
          o[i].x += p*vv.x; o[i].y += p*vv.y; o[i].z += p*vv.z; o[i].w += p*vv.w;
        }
      }
    }
  }
  float inv = 1.f / l;
  bf16* op = (h < 4 ? ctxf : ctxb) + ((size_t)b * SLEN + tid) * 256 + (h & 3) * 64;
#pragma unroll
  for (int i = 0; i < 16; ++i) {
    op[i * 4 + 0] = __float2bfloat16(o[i].x * inv);
    op[i * 4 + 1] = __float2bfloat16(o[i].y * inv);
    op[i * 4 + 2] = __float2bfloat16(o[i].z * inv);
    op[i * 4 + 3] = __float2bfloat16(o[i].w * inv);
  }
}

// ---------------------------------------------------------------------------
// Small kernels
// ---------------------------------------------------------------------------
__global__ __launch_bounds__(256) void f2b_kernel(
    const float* __restrict__ src, bf16* __restrict__ dst, int n)
{
  int i = blockIdx.x * 256 + threadIdx.x;
  if (i < n) dst[i] = __float2bfloat16(src[i]);
}

__global__ __launch_bounds__(256) void embed_kernel(
    const float* __restrict__ src, const float* __restrict__ ew,
    const float* __restrict__ eb, bf16* __restrict__ out)
{
  size_t row = blockIdx.x;
  int i = threadIdx.x;
  out[row * 256 + i] = __float2bfloat16(src[row] * ew[i] + eb[i]);
}

__device__ __forceinline__ float breduce_sum(float v, float* sh) {
  int tid = threadIdx.x;
  sh[tid] = v; __syncthreads();
  for (int s = 128; s > 0; s >>= 1) {
    if (tid < s) sh[tid] += sh[tid + s];
    __syncthreads();
  }
  float r = sh[0]; __syncthreads();
  return r;
}

__global__ __launch_bounds__(256) void stats_kernel(
    const float* __restrict__ src, const float* __restrict__ mask,
    float* __restrict__ stats4)
{
  __shared__ float sh[256];
  const int b = blockIdx.x, t = threadIdx.x;
  const float m = mask[b * 256 + t];
  const float x = src[b * 256 + t] * m;
  float sum = breduce_sum(x, sh);
  float mean = sum * (1.f / 256.f);
  float d = x - mean;
  float var = breduce_sum(d * d, sh) / 255.f;
  float sd = fmaxf(sqrtf(var), 1e-6f);
  float denom = fmaxf(breduce_sum(m, sh), 1e-6f);
  float pk = breduce_sum((x > 1.f + 2.f * sd) ? 1.f : 0.f, sh) / denom;
  float e1 = x - 1.f;
  float sk = (breduce_sum(e1 * e1 * e1 * m, sh) * (1.f / 256.f)) / (sd * sd * sd + 1e-6f);
  float etot = 0.f;
  for (int f = 0; f < 5; ++f) {
    double ang = -2.0 * 3.14159265358979323846 * (double)(f * t) / 256.0;
    float re = breduce_sum(x * (float)cos(ang), sh);
    float im = breduce_sum(x * (float)sin(ang), sh);
    etot += sqrtf(re * re + im * im);
  }
  if (t == 0) {
    stats4[b * 4 + 0] = sd;
    stats4[b * 4 + 1] = pk;
    stats4[b * 4 + 2] = sk;
    stats4[b * 4 + 3] = etot / 5.f;
  }
}

__global__ __launch_bounds__(256) void zmeanmax_kernel(
    const float* __restrict__ z_e, const float* __restrict__ mask,
    float* __restrict__ pooled)
{
  const int b = blockIdx.x, e = threadIdx.x;
  float acc = 0.f, mx = -INFINITY, dsum = 0.f;
  const float* zp = z_e + (size_t)b * SLEN * 256 + e;
  const float* mp = mask + (size_t)b * SLEN;
  for (int t = 0; t < SLEN; ++t) {
    float mt = mp[t];
    float v = zp[(size_t)t * 256] * mt;
    acc += v; mx = fmaxf(mx, v); dsum += mt;
  }
  float denom = fmaxf(dsum, 1e-6f);
  pooled[(size_t)b * 768 + e] = acc / denom;
  pooled[(size_t)b * 768 + 256 + e] = mx;
}

__global__ __launch_bounds__(256) void rowsq_kernel(
    const float* __restrict__ a, float* __restrict__ out)
{
  __shared__ float sh[256];
  const int r = blockIdx.x;
  float v = a[(size_t)r * 256 + threadIdx.x];
  float s = breduce_sum(v * v, sh);
  if (threadIdx.x == 0) out[r] = s;
}

// JAX threefry2x32 (key=(0,42)), partitionable scheme: bits = b1 ^ b2 of
// threefry2x32(key, (0, i)) — verified bit-exact vs dataset (R4 pass).
__device__ __forceinline__ uint2 threefry2x32(uint32_t k0, uint32_t k1,
                                              uint32_t x0, uint32_t x1) {
  uint32_t k2 = k0 ^ k1 ^ 0x1BD11BDAu;
  x0 += k0; x1 += k1;
#define TFR(r) { x0 += x1; x1 = (x1 << r) | (x1 >> (32 - r)); x1 ^= x0; }
  TFR(13) TFR(15) TFR(26) TFR(6)
  x0 += k1; x1 += k2 + 1u;
  TFR(17) TFR(29) TFR(16) TFR(24)
  x0 += k2; x1 += k0 + 2u;
  TFR(13) TFR(15) TFR(26) TFR(6)
  x0 += k0; x1 += k1 + 3u;
  TFR(17) TFR(29) TFR(16) TFR(24)
  x0 += k1; x1 += k2 + 4u;
  TFR(13) TFR(15) TFR(26) TFR(6)
  x0 += k2; x1 += k0 + 5u;
#undef TFR
  return make_uint2(x0, x1);
}

__global__ __launch_bounds__(256) void sample_kernel(
    const float* __restrict__ dots, const float* __restrict__ p2,
    const float* __restrict__ c2, float* __restrict__ out_idx_f,
    int* __restrict__ idx_i)
{
  const int b = blockIdx.x, tid = threadIdx.x;
  const float p2b = p2[b];
  float best = -INFINITY; int bidx = 0;
  for (int k = tid; k < 16384; k += 256) {
    float d2 = fmaxf(p2b + c2[k] - 2.f * dots[(size_t)b * 16384 + k], 0.f);
    float logit = -sqrtf(d2) / 0.7f;
    uint32_t i = (uint32_t)b * 16384u + (uint32_t)k;
    uint2 r = threefry2x32(0u, 42u, 0u, i);
    uint32_t bits = r.x ^ r.y;
    float u = __uint_as_float((bits >> 9) | 0x3f800000u) - 1.0f;
    u = u + 1.17549435e-38f;
    u = fmaxf(u, 1.17549435e-38f);
    float g = -logf(-logf(u));
    float val = logit + g;
    if (val > best) { best = val; bidx = k; }
  }
  __shared__ float bvs[256];
  __shared__ int bks[256];
  bvs[tid] = best; bks[tid] = bidx;
  __syncthreads();
  for (int s = 128; s > 0; s >>= 1) {
    if (tid < s) {
      if (bvs[tid + s] > bvs[tid] ||
          (bvs[tid + s] == bvs[tid] && bks[tid + s] < bks[tid])) {
        bvs[tid] = bvs[tid + s]; bks[tid] = bks[tid + s];
      }
    }
    __syncthreads();
  }
  if (tid == 0) {
    idx_i[b] = bks[0];
    out_idx_f[b] = (float)bks[0];
  }
}

__global__ __launch_bounds__(256) void zqrow_kernel(
    const float* __restrict__ cb, const int* __restrict__ idx,
    float* __restrict__ zqrow)
{
  const int b = blockIdx.x, e = threadIdx.x;
  zqrow[(size_t)b * 256 + e] = cb[(size_t)idx[b] * 256 + e];
}

__global__ __launch_bounds__(256) void zqbcast_kernel(
    const float* __restrict__ zqrow, float* __restrict__ out)
{
  const size_t row = blockIdx.x;
  const int e = threadIdx.x;
  out[row * 256 + e] = zqrow[(row >> 8) * 256 + e];
}

__global__ __launch_bounds__(256) void recon_kernel(
    const bf16* __restrict__ hf, const bf16* __restrict__ hb,
    const float* __restrict__ ow, const float* __restrict__ ob,
    float* __restrict__ out)
{
  const int row = blockIdx.x * 4 + (threadIdx.x >> 6);
  const int lane = threadIdx.x & 63;
  const bf16* pf = hf + (size_t)row * 256;
  const bf16* pb = hb + (size_t)row * 256;
  float s = 0.f;
  for (int i = lane; i < 256; i += 64)
    s += __bfloat162float(pf[i]) * ow[i] + __bfloat162float(pb[i]) * ow[256 + i];
  for (int off = 32; off > 0; off >>= 1) s += __shfl_down(s, off);
  if (lane == 0) out[row] = s + ob[0];
}

// ---------------------------------------------------------------------------
static inline void gemm_bf16(const bf16* A0, const bf16* A1, const bf16* W,
                             const float* bias, const float* rowmask,
                             float* Cf, bf16* Cb, int M, int N, int K,
                             int lda, int ldc, int flags, int rb,
                             hipStream_t s) {
  dim3 g(N / 128, M / 128), b(256);
  int kHalf = A1 ? 256 : K;
  hipLaunchKernelGGL(gemm_bf16_kernel, g, b, 0, s, A0, A1, W, bias, rowmask,
                     Cf, Cb, M, N, K, lda, ldc, flags, rb, kHalf);
}

static inline void gemm(const float* A, const float* W, const float* bias,
                        const float* rowmask, float* C, int M, int N, int K,
                        int lda, int ldw, int ldc, int flags, hipStream_t s) {
  dim3 g(N / TN, M / TM), b(256);
  hipLaunchKernelGGL(gemm_kernel, g, b, 0, s, A, W, bias, rowmask, C,
                     M, N, K, lda, ldw, ldc, flags);
}

// Chunked BiLSTM layer with bf16 activations.
static void bilstm_bf16(const bf16* inF, const bf16* inB, const bf16* Wb,
                        int Kdim, const float* bg, const float* whh,
                        const float* pmask, bf16* yf, bf16* yb, float* gates,
                        float* h_g, float* c_g, hipStream_t st) {
  const int M = BATCH * TC;  // 16384
  for (int c = 0; c < SLEN / TC; ++c) {
    int t0f = c * TC;
    int t0b = SLEN - (c + 1) * TC;
    for (int dir = 0; dir < 2; ++dir) {
      int t0 = dir ? t0b : t0f;
      gemm_bf16(inF + (size_t)t0 * 256, inB ? inB + (size_t)t0 * 256 : nullptr,
                Wb + (size_t)dir * NGATE * Kdim, bg + dir * NGATE, nullptr,
                gates + dir * NGATE, nullptr, M, NGATE, Kdim, 256, 2048, 0, 5, st);
    }
    hipLaunchKernelGGL(lstm_kernel, dim3(128), dim3(1024), 0, st,
                       gates, whh, pmask, yf, yb, h_g, c_g,
                       t0f, TC, (c == 0) ? 1 : 0, 2048, TC * 2048);
  }
}

extern "C" void kernel_launch(void* const* d_in, const int* in_sizes, int n_in,
                              void* d_out, int out_size, void* d_ws, size_t ws_size,
                              hipStream_t stream) {
  (void)in_sizes; (void)n_in; (void)out_size;
  const float* src     = (const float*)d_in[0];
  const float* pmask   = (const float*)d_in[1];
  const float* emb_w   = (const float*)d_in[3];
  const float* emb_b   = (const float*)d_in[4];
  const float* e0_Wih  = (const float*)d_in[5];
  const float* e0_Whh  = (const float*)d_in[6];
  const float* e0_b    = (const float*)d_in[7];
  const float* e1_Wih  = (const float*)d_in[8];
  const float* e1_Whh  = (const float*)d_in[9];
  const float* e1_b    = (const float*)d_in[10];
  const float* a_in_w  = (const float*)d_in[11];
  const float* a_in_b  = (const float*)d_in[12];
  const float* a_out_w = (const float*)d_in[13];
  const float* a_out_b = (const float*)d_in[14];
  const float* fc_w    = (const float*)d_in[15];
  const float* fc_b    = (const float*)d_in[16];
  const float* st_w    = (const float*)d_in[17];
  const float* st_b    = (const float*)d_in[18];
  const float* po_w    = (const float*)d_in[19];
  const float* po_b    = (const float*)d_in[20];
  const float* cb      = (const float*)d_in[21];
  const float* dfc_w   = (const float*)d_in[22];
  const float* dfc_b   = (const float*)d_in[23];
  const float* da_in_w = (const float*)d_in[24];
  const float* da_in_b = (const float*)d_in[25];
  const float* da_out_w= (const float*)d_in[26];
  const float* da_out_b= (const float*)d_in[27];
  const float* d0_Wih  = (const float*)d_in[28];
  const float* d0_Whh  = (const float*)d_in[29];
  const float* d0_b    = (const float*)d_in[30];
  const float* d1_Wih  = (const float*)d_in[31];
  const float* d1_Whh  = (const float*)d_in[32];
  const float* d1_b    = (const float*)d_in[33];
  const float* out_w   = (const float*)d_in[34];
  const float* out_b   = (const float*)d_in[35];

  float* out = (float*)d_out;
  float* ws  = (float*)d_ws;

  // ---- workspace layout (float units): ~305 MB ----
  float* S3   = ws;                                   // 33,554,432 f (gates/QKV/dots)
  bf16*  S1b  = (bf16*)(ws + 33554432);               // BS*256 bf16
  bf16*  S2b  = (bf16*)(ws + 33554432 + 16777216);
  bf16*  Xb   = (bf16*)(ws + 33554432 + 2 * 16777216);        // 16384*512 bf16
  bf16*  WbB  = (bf16*)(ws + 33554432 + 2 * 16777216 + 4194304); // 3,801,088 bf16
  float* SM   = ws + 33554432 + 2 * 16777216 + 4194304 + 1900544;
  float* h_state = SM;
  float* c_state = SM + 262144;
  float* pooled  = SM + 524288;
  float* phrase  = SM + 917504;
  float* stats4  = SM + 1048576;
  float* p2      = SM + 1050624;
  float* c2      = SM + 1051136;
  int*   idx_i   = (int*)(SM + 1067520);
  float* zqrow   = SM + 1068032;
  float* hd      = SM + 1199104;
  float* vb      = SM + 1461248;
  float* dab     = SM + 1723392;
  float* xwdec   = SM + 1985536;
  const size_t NEED_BYTES =
      (33554432ull + 2 * 16777216 + 4194304 + 1900544 + 3034112) * 4;
  if (ws_size < NEED_BYTES) return;

  // bf16 weight sub-buffers
  bf16* e0Wb  = WbB;                 // 2*1024*256
  bf16* e1Wb  = WbB + 524288;        // 2*1024*512
  bf16* ainWb = WbB + 1572864;       // 1536*512
  bf16* aoutWb= WbB + 2359296;       // 512*512
  bf16* fcWb  = WbB + 2621440;       // 256*512
  bf16* d1Wb  = WbB + 2752512;       // 2*1024*512

  float* o_recon = out;
  float* o_ze    = out + 131072;
  float* o_zq    = out + 33685504;
  float* o_idx   = out + 67239936;
  bf16*  Eb     = (bf16*)o_ze;       // embed scratch (dead after e0 GEMMs)
  // BOTH ctx halves live in the o_zq region (67.1M bf16 slot fits 2x 33.5M):
  // o_zq is only written by zqbcast AFTER attention is fully consumed. This
  // avoids R5's byte-aliasing NaN (fc's fp32 z_e writes stomped bf16 ctx).
  bf16*  ctxf_b = (bf16*)o_zq;
  bf16*  ctxb_b = (bf16*)o_zq + 33554432;

  const int BS = BATCH * SLEN;

  // ---- weight conversions to bf16 ----
  hipLaunchKernelGGL(f2b_kernel, dim3(2048), dim3(256), 0, stream, e0_Wih, e0Wb, 524288);
  hipLaunchKernelGGL(f2b_kernel, dim3(4096), dim3(256), 0, stream, e1_Wih, e1Wb, 1048576);
  hipLaunchKernelGGL(f2b_kernel, dim3(3072), dim3(256), 0, stream, a_in_w, ainWb, 786432);
  hipLaunchKernelGGL(f2b_kernel, dim3(1024), dim3(256), 0, stream, a_out_w, aoutWb, 262144);
  hipLaunchKernelGGL(f2b_kernel, dim3(512),  dim3(256), 0, stream, fc_w, fcWb, 131072);
  hipLaunchKernelGGL(f2b_kernel, dim3(4096), dim3(256), 0, stream, d1_Wih, d1Wb, 1048576);

  // ---- encoder ----
  hipLaunchKernelGGL(embed_kernel, dim3(BS), dim3(256), 0, stream,
                     src, emb_w, emb_b, Eb);
  bilstm_bf16(Eb, nullptr, e0Wb, 256, e0_b, e0_Whh, pmask,
              S1b, S2b, S3, h_state, c_state, stream);
  bilstm_bf16(S1b, S2b, e1Wb, 512, e1_b, e1_Whh, pmask,
              S1b, S2b, S3, h_state, c_state, stream);   // in-place

  // attention, batch-chunked: QKV (fp32) into S3, ctx (bf16) into o_zq region
  for (int b0 = 0; b0 < BATCH; b0 += BC) {
    gemm_bf16(S1b + (size_t)b0 * SLEN * 256, S2b + (size_t)b0 * SLEN * 256,
              ainWb, a_in_b, nullptr, S3, nullptr,
              BC * SLEN, 1536, 512, 256, 1536, 0, -1, stream);
    hipLaunchKernelGGL(attn_kernel, dim3(8, BC), dim3(256), 0, stream,
                       S3, pmask, ctxf_b, ctxb_b, b0);
  }
  // attn-out (bf16 out) then z_e (fp32 out), batch-chunked
  for (int b0 = 0; b0 < BATCH; b0 += BC) {
    gemm_bf16(ctxf_b + (size_t)b0 * SLEN * 256, ctxb_b + (size_t)b0 * SLEN * 256,
              aoutWb, a_out_b, pmask + (size_t)b0 * SLEN, nullptr, Xb,
              BC * SLEN, 512, 512, 256, 512, GF_ROWMASK, -1, stream);
    gemm_bf16(Xb, nullptr, fcWb, fc_b, nullptr,
              o_ze + (size_t)b0 * SLEN * 256, nullptr,
              BC * SLEN, 256, 512, 512, 256, 0, -1, stream);
  }

  // ---- pooling / stats / phrase ----
  hipLaunchKernelGGL(zmeanmax_kernel, dim3(512), dim3(256), 0, stream,
                     o_ze, pmask, pooled);
  hipLaunchKernelGGL(stats_kernel, dim3(512), dim3(256), 0, stream,
                     src, pmask, stats4);
  gemm(stats4, st_w, st_b, nullptr, pooled + 512, 512, 256, 4,
       4, 4, 768, 0, stream);
  gemm(pooled, po_w, po_b, nullptr, phrase, 512, 256, 768,
       768, 768, 256, 0, stream);

  // ---- VQ: fp32 distances + exact JAX categorical sampling ----
  hipLaunchKernelGGL(rowsq_kernel, dim3(512), dim3(256), 0, stream, phrase, p2);
  hipLaunchKernelGGL(rowsq_kernel, dim3(16384), dim3(256), 0, stream, cb, c2);
  gemm(phrase, cb, nullptr, nullptr, S3, 512, 16384, 256,
       256, 256, 16384, 0, stream);
  hipLaunchKernelGGL(sample_kernel, dim3(512), dim3(256), 0, stream,
                     S3, p2, c2, o_idx, idx_i);
  hipLaunchKernelGGL(zqrow_kernel, dim3(512), dim3(256), 0, stream,
                     cb, idx_i, zqrow);
  hipLaunchKernelGGL(zqbcast_kernel, dim3(BS), dim3(256), 0, stream,
                     zqrow, o_zq);

  // ---- decoder prelude (fp32 naive, tiny): fc -> collapsed MHA -> xW ----
  gemm(zqrow, dfc_w, dfc_b, nullptr, hd, 512, 512, 256,
       256, 256, 512, GF_RELU, stream);
  gemm(hd, da_in_w + (size_t)1024 * 512, da_in_b + 1024, nullptr, vb,
       512, 512, 512, 512, 512, 512, 0, stream);
  gemm(vb, da_out_w, da_out_b, nullptr, dab, 512, 512, 512,
       512, 512, 512, 0, stream);
  gemm(dab, d0_Wih, d0_b, nullptr, xwdec, 512, 2048, 512,
       512, 512, 2048, 0, stream);

  // ---- decoder LSTMs + output projection ----
  hipLaunchKernelGGL(lstm_kernel, dim3(128), dim3(1024), 0, stream,
                     xwdec, d0_Whh, pmask, S1b, S2b, h_state, c_state,
                     0, SLEN, 1, 0, 2048);
  bilstm_bf16(S1b, S2b, d1Wb, 512, d1_b, d1_Whh, pmask,
              S1b, S2b, S3, h_state, c_state, stream);   // in-place
  hipLaunchKernelGGL(recon_kernel, dim3(BS / 4), dim3(256), 0, stream,
                     S1b, S2b, out_w, out_b, o_recon);
}

// Round 7
// 18439.595 us; speedup vs baseline: 2.7938x; 2.3349x over previous
//
#include <hip/hip_runtime.h>
#include <hip/hip_bf16.h>
#include <math.h>
#include <stdint.h>

#define BATCH 512
#define SLEN 256
#define HDIM 256     // hidden per direction
#define NGATE 1024   // 4*HDIM
#define TC 32        // LSTM time-chunk
#define BC 64        // attention batch-chunk

typedef __hip_bfloat16 bf16;
typedef __attribute__((ext_vector_type(8))) short short8;   // 8 bf16 = 4 VGPRs
typedef __attribute__((ext_vector_type(4))) float f32x4;

#define GF_RELU 1
#define GF_ROWMASK 2
#define GF_ACCUM 4

// ---------------------------------------------------------------------------
// bf16 MFMA GEMM: C[M,N] = concatK(A0,A1)[M,K] @ W[N,K]^T (+bias fp32).
// (unchanged from R6 — validated passing)
// ---------------------------------------------------------------------------
__global__ __launch_bounds__(256) void gemm_bf16_kernel(
    const bf16* __restrict__ A0, const bf16* __restrict__ A1,
    const bf16* __restrict__ W, const float* __restrict__ bias,
    const float* __restrict__ rowmask, float* __restrict__ Cf,
    bf16* __restrict__ Cb, int M, int N, int K, int lda, int ldc,
    int flags, int rb_shift, int kHalf)
{
  __shared__ short As[128][40];   // 32 k + 8 pad
  __shared__ short Bs[128][40];
  const int tid = threadIdx.x;
  const int m0 = blockIdx.y * 128, n0 = blockIdx.x * 128;
  const int wave = tid >> 6, lane = tid & 63;
  const int wm = (wave & 1) * 64, wn = (wave >> 1) * 64;
  const int fm = lane & 15, fq = (lane >> 4) * 8;

  f32x4 acc[4][4];
#pragma unroll
  for (int i = 0; i < 4; ++i)
#pragma unroll
    for (int j = 0; j < 4; ++j) acc[i][j] = (f32x4){0.f, 0.f, 0.f, 0.f};

  for (int k0 = 0; k0 < K; k0 += 32) {
    const bf16* Asrc = (A1 && k0 >= kHalf) ? A1 : A0;
    const int kk = (A1 && k0 >= kHalf) ? (k0 - kHalf) : k0;
#pragma unroll
    for (int p = 0; p < 2; ++p) {
      int idx = p * 256 + tid;          // 512 chunks of 16B
      int r = idx >> 2, q = idx & 3;
      int rl = m0 + r;
      int pr = (rb_shift >= 0)
                   ? ((rl >> rb_shift) * SLEN + (rl & ((1 << rb_shift) - 1)))
                   : rl;
      *(uint4*)&As[r][q * 8] =
          *(const uint4*)(Asrc + (size_t)pr * lda + kk + q * 8);
      *(uint4*)&Bs[r][q * 8] =
          *(const uint4*)(W + (size_t)(n0 + r) * K + k0 + q * 8);
    }
    __syncthreads();
    short8 af[4], bfr[4];
#pragma unroll
    for (int mi = 0; mi < 4; ++mi)
      af[mi] = *(short8*)&As[wm + mi * 16 + fm][fq];
#pragma unroll
    for (int ni = 0; ni < 4; ++ni)
      bfr[ni] = *(short8*)&Bs[wn + ni * 16 + fm][fq];
#pragma unroll
    for (int mi = 0; mi < 4; ++mi)
#pragma unroll
      for (int ni = 0; ni < 4; ++ni)
        acc[mi][ni] = __builtin_amdgcn_mfma_f32_16x16x32_bf16(
            af[mi], bfr[ni], acc[mi][ni], 0, 0, 0);
    __syncthreads();
  }

  const int cr = (lane >> 4) * 4, cc = lane & 15;
#pragma unroll
  for (int mi = 0; mi < 4; ++mi) {
#pragma unroll
    for (int r = 0; r < 4; ++r) {
      int m = m0 + wm + mi * 16 + cr + r;
      float rm = (flags & GF_ROWMASK) ? rowmask[m] : 1.f;
#pragma unroll
      for (int ni = 0; ni < 4; ++ni) {
        int n = n0 + wn + ni * 16 + cc;
        float v = acc[mi][ni][r] + (bias ? bias[n] : 0.f);
        if (flags & GF_RELU) v = fmaxf(v, 0.f);
        v *= rm;
        if (Cb) Cb[(size_t)m * ldc + n] = __float2bfloat16(v);
        else    Cf[(size_t)m * ldc + n] = v;
      }
    }
  }
}

// ---------------------------------------------------------------------------
// fp32 naive GEMM (small ops only: stats K=4, pool, VQ dots, decoder prelude)
// ---------------------------------------------------------------------------
#define TM 128
#define TN 128
#define TKK 16

__global__ __launch_bounds__(256) void gemm_kernel(
    const float* __restrict__ A, const float* __restrict__ W,
    const float* __restrict__ bias, const float* __restrict__ rowmask,
    float* __restrict__ C, int M, int N, int K,
    int lda, int ldw, int ldc, int flags)
{
  __shared__ float As[TKK][TM + 4];
  __shared__ float Ws[TKK][TN + 4];
  const int tid = threadIdx.x;
  const int tx = tid & 15, ty = tid >> 4;
  const int m0 = blockIdx.y * TM;
  const int n0 = blockIdx.x * TN;
  float acc[8][8];
#pragma unroll
  for (int i = 0; i < 8; ++i)
#pragma unroll
    for (int j = 0; j < 8; ++j) acc[i][j] = 0.f;

  for (int k0 = 0; k0 < K; k0 += TKK) {
#pragma unroll
    for (int p = 0; p < 2; ++p) {
      int f4 = p * 256 + tid;
      int row = f4 >> 2;
      int kk = (f4 & 3) * 4;
      float4 va = make_float4(0.f, 0.f, 0.f, 0.f);
      float4 vw = make_float4(0.f, 0.f, 0.f, 0.f);
      if (k0 + kk < K) {
        va = *(const float4*)(A + (size_t)(m0 + row) * lda + k0 + kk);
        vw = *(const float4*)(W + (size_t)(n0 + row) * ldw + k0 + kk);
      }
      As[kk + 0][row] = va.x; As[kk + 1][row] = va.y;
      As[kk + 2][row] = va.z; As[kk + 3][row] = va.w;
      Ws[kk + 0][row] = vw.x; Ws[kk + 1][row] = vw.y;
      Ws[kk + 2][row] = vw.z; Ws[kk + 3][row] = vw.w;
    }
    __syncthreads();
#pragma unroll
    for (int kk = 0; kk < TKK; ++kk) {
      float a[8], w[8];
      float4 t0 = *(const float4*)&As[kk][ty * 8];
      float4 t1 = *(const float4*)&As[kk][ty * 8 + 4];
      a[0]=t0.x; a[1]=t0.y; a[2]=t0.z; a[3]=t0.w;
      a[4]=t1.x; a[5]=t1.y; a[6]=t1.z; a[7]=t1.w;
      float4 s0 = *(const float4*)&Ws[kk][tx * 8];
      float4 s1 = *(const float4*)&Ws[kk][tx * 8 + 4];
      w[0]=s0.x; w[1]=s0.y; w[2]=s0.z; w[3]=s0.w;
      w[4]=s1.x; w[5]=s1.y; w[6]=s1.z; w[7]=s1.w;
#pragma unroll
      for (int i = 0; i < 8; ++i)
#pragma unroll
        for (int j = 0; j < 8; ++j) acc[i][j] += a[i] * w[j];
    }
    __syncthreads();
  }
  float bv[8];
#pragma unroll
  for (int j = 0; j < 8; ++j) bv[j] = bias ? bias[n0 + tx * 8 + j] : 0.f;
#pragma unroll
  for (int i = 0; i < 8; ++i) {
    int m = m0 + ty * 8 + i;
    float rm = (flags & GF_ROWMASK) ? rowmask[m] : 1.f;
    float* cp = C + (size_t)m * ldc + n0 + tx * 8;
    float o[8];
#pragma unroll
    for (int j = 0; j < 8; ++j) {
      float v = acc[i][j] + bv[j];
      if (flags & GF_ACCUM) v += cp[j];
      if (flags & GF_RELU) v = fmaxf(v, 0.f);
      o[j] = v * rm;
    }
    *(float4*)cp = make_float4(o[0], o[1], o[2], o[3]);
    *(float4*)(cp + 4) = make_float4(o[4], o[5], o[6], o[7]);
  }
}

// ---------------------------------------------------------------------------
// Whh reshuffle: fp32 [2,1024,256] -> bf16 swizzled so lstm thread (u,ksub)
// reads contiguous 16B per (gate-row, k-octet):
//   W2[dir][((m*1024 + row)*4 + ksub)*8 + j] = Whh[dir][row][m*32+ksub*8+j]
// ---------------------------------------------------------------------------
__global__ __launch_bounds__(256) void whh2b_kernel(
    const float* __restrict__ src, bf16* __restrict__ dst)
{
  int idx = blockIdx.x * 256 + threadIdx.x;   // [0, 524288)
  int dir = idx >> 18;
  int rem = idx & 262143;
  int row = rem >> 8;
  int k   = rem & 255;
  int m = k >> 5, kk = k & 31, ksub = kk >> 3, j = kk & 7;
  dst[dir * 262144 + ((m * 1024 + row) * 4 + ksub) * 8 + j] =
      __float2bfloat16(src[idx]);
}

__device__ __forceinline__ void unpack8(uint4 w, float* f) {
  f[0] = __uint_as_float(w.x << 16);
  f[1] = __uint_as_float(w.x & 0xffff0000u);
  f[2] = __uint_as_float(w.y << 16);
  f[3] = __uint_as_float(w.y & 0xffff0000u);
  f[4] = __uint_as_float(w.z << 16);
  f[5] = __uint_as_float(w.z & 0xffff0000u);
  f[6] = __uint_as_float(w.w << 16);
  f[7] = __uint_as_float(w.w & 0xffff0000u);
}

// ---------------------------------------------------------------------------
// BiLSTM chunk kernel, v2. grid = 256 blocks (dir = bx>>7, 4 batches =
// (bx&127)*4), 1024 threads = (u in [0,256)) x (ksub in [0,4)).
// Thread k-set: k = m*32 + ksub*8 + j (m in [0,8), j in [0,8)) ->
//   - bf16 weights from swizzled W2: 1 x 16B fully-coalesced load per (r,m)
//   - LDS h reads spread over bank quads {0,8,16,24} -> conflict-free
// shfl_xor(1,2) completes dots over ksub; lane updates batch g=ksub of unit
// u (c in 1 reg). Double-buffered h in LDS -> ONE barrier per step.
// ---------------------------------------------------------------------------
__global__ __launch_bounds__(1024) void lstm_kernel(
    const float* __restrict__ xw, const bf16* __restrict__ w2,
    const float* __restrict__ mask, bf16* __restrict__ yf,
    bf16* __restrict__ yb, float* __restrict__ h_g, float* __restrict__ c_g,
    int t0, int nsteps, int first, int xw_stride_t, int xw_stride_b)
{
  __shared__ float h_s[2][4][264];   // row pad to 264 (stride mod 32 = 8)
  const int tid = threadIdx.x;
  const int u = tid >> 2;
  const int ksub = tid & 3;
  const int dir = blockIdx.x >> 7;
  const int b0 = (blockIdx.x & 127) * 4;
  const int b = b0 + ksub;
  const size_t stbase = (size_t)dir * BATCH * HDIM;

  {
    int g = tid >> 8, ii = tid & 255;
    h_s[0][g][ii] = first ? 0.f : h_g[stbase + (size_t)(b0 + g) * HDIM + ii];
  }
  float c_own = first ? 0.f : c_g[stbase + (size_t)b * HDIM + u];
  __syncthreads();

  // ksub*8 baked into base; per (r,m) add (m*1024 + r*256 + u)*32
  const bf16* w2base = w2 + (size_t)dir * 262144 + ksub * 8;
  bf16* yd = dir ? yb : yf;
  int cur = 0;

  for (int s = 0; s < nsteps; ++s) {
    const int t = dir ? (SLEN - 1 - (t0 + s)) : (t0 + s);
    const int xrow = dir ? (nsteps - 1 - s) : s;
    float acc[4][4];
#pragma unroll
    for (int r = 0; r < 4; ++r)
#pragma unroll
      for (int g = 0; g < 4; ++g) acc[r][g] = 0.f;

#pragma unroll 2
    for (int m = 0; m < 8; ++m) {
      uint4 wv[4];
#pragma unroll
      for (int r = 0; r < 4; ++r)
        wv[r] = *(const uint4*)(w2base + (size_t)(m * 1024 + r * 256 + u) * 32);
      float wf[4][8];
#pragma unroll
      for (int r = 0; r < 4; ++r) unpack8(wv[r], wf[r]);
#pragma unroll
      for (int g = 0; g < 4; ++g) {
        float4 h0 = *(const float4*)&h_s[cur][g][m * 32 + ksub * 8];
        float4 h1 = *(const float4*)&h_s[cur][g][m * 32 + ksub * 8 + 4];
#pragma unroll
        for (int r = 0; r < 4; ++r) {
          acc[r][g] += wf[r][0]*h0.x + wf[r][1]*h0.y + wf[r][2]*h0.z +
                       wf[r][3]*h0.w + wf[r][4]*h1.x + wf[r][5]*h1.y +
                       wf[r][6]*h1.z + wf[r][7]*h1.w;
        }
      }
    }
    // complete dots across the 4 k-groups (quad lanes: same u, ksub 0..3)
#pragma unroll
    for (int r = 0; r < 4; ++r)
#pragma unroll
      for (int g = 0; g < 4; ++g) {
        float v = acc[r][g];
        v += __shfl_xor(v, 1);
        v += __shfl_xor(v, 2);
        acc[r][g] = v;
      }

    const float* xwp = xw + (size_t)b * xw_stride_b +
                       (size_t)xrow * xw_stride_t + dir * NGATE;
    float gi = acc[0][ksub] + xwp[u];
    float gf = acc[1][ksub] + xwp[u + 256];
    float gg = acc[2][ksub] + xwp[u + 512];
    float go = acc[3][ksub] + xwp[u + 768];
    float mt = mask[(size_t)b * SLEN + t];
    float si = 1.f / (1.f + expf(-gi));
    float sf = 1.f / (1.f + expf(-gf));
    float so = 1.f / (1.f + expf(-go));
    float cn = sf * c_own + si * tanhf(gg);
    float hn = so * tanhf(cn);
    float hp = h_s[cur][ksub][u];
    float hnew = mt * hn + (1.f - mt) * hp;
    c_own = mt * cn + (1.f - mt) * c_own;
    h_s[cur ^ 1][ksub][u] = hnew;   // write other buffer: no read/write race
    yd[((size_t)b * SLEN + t) * HDIM + u] = __float2bfloat16(hnew * mt);
    __syncthreads();
    cur ^= 1;
  }

  {
    int g = tid >> 8, ii = tid & 255;
    h_g[stbase + (size_t)(b0 + g) * HDIM + ii] = h_s[cur][g][ii];
  }
  c_g[stbase + (size_t)b * HDIM + u] = c_own;
}

// ---------------------------------------------------------------------------
// Encoder MHA over a batch chunk (fp32 QKV in, bf16 ctx out). (unchanged)
// ---------------------------------------------------------------------------
__global__ __launch_bounds__(256) void attn_kernel(
    const float* __restrict__ qkv, const float* __restrict__ mask,
    bf16* __restrict__ ctxf, bf16* __restrict__ ctxb, int b0)
{
  __shared__ float Ks[128][64];
  const int h = blockIdx.x;
  const int bb = blockIdx.y;
  const int b = b0 + bb;
  const int tid = threadIdx.x;
  const float* base = qkv + (size_t)bb * SLEN * 1536;

  float4 q[16], o[16];
  const float* qp = base + (size_t)tid * 1536 + h * 64;
#pragma unroll
  for (int i = 0; i < 16; ++i) {
    q[i] = *(const float4*)(qp + i * 4);
    o[i] = make_float4(0.f, 0.f, 0.f, 0.f);
  }
  float m = -1e30f, l = 0.f;
  for (int half = 0; half < 2; ++half) {
    __syncthreads();
    for (int i = tid; i < 128 * 16; i += 256) {
      int krow = i >> 4, dq = i & 15;
      *(float4*)&Ks[krow][dq * 4] = *(const float4*)(
          base + (size_t)(half * 128 + krow) * 1536 + 512 + h * 64 + dq * 4);
    }
    __syncthreads();
    for (int k2 = 0; k2 < 128; ++k2) {
      int k = half * 128 + k2;
      float mk = mask[(size_t)b * SLEN + k];
      if (mk > 0.f) {
        float s = 0.f;
#pragma unroll
        for (int i = 0; i < 16; ++i) {
          float4 kv = *(const float4*)&Ks[k2][i * 4];
          s += q[i].x*kv.x + q[i].y*kv.y + q[i].z*kv.z + q[i].w*kv.w;
        }
        s *= 0.125f;
        if (s > m) {
          float corr = expf(m - s);
          l *= corr;
#pragma unroll
          for (int i = 0; i < 16; ++i) {
            o[i].x *= corr; o[i].y *= corr; o[i].z *= corr; o[i].w *= corr;
          }
          m = s;
        }
        float p = expf(s - m);
        l += p;
        const float* vp = base + (size_t)k * 1536 + 1024 + h * 64;
#pragma unroll
        for (int i = 0; i < 16; ++i) {
          float4 vv = *(const float4*)(vp + i * 4);
          o[i].x += p*vv.x; o[i].y += p*vv.y; o[i].z += p*vv.z; o[i].w += p*vv.w;
        }
      }
    }
  }
  float inv = 1.f / l;
  bf16* op = (h < 4 ? ctxf : ctxb) + ((size_t)b * SLEN + tid) * 256 + (h & 3) * 64;
#pragma unroll
  for (int i = 0; i < 16; ++i) {
    op[i * 4 + 0] = __float2bfloat16(o[i].x * inv);
    op[i * 4 + 1] = __float2bfloat16(o[i].y * inv);
    op[i * 4 + 2] = __float2bfloat16(o[i].z * inv);
    op[i * 4 + 3] = __float2bfloat16(o[i].w * inv);
  }
}

// ---------------------------------------------------------------------------
// Small kernels (unchanged)
// ---------------------------------------------------------------------------
__global__ __launch_bounds__(256) void f2b_kernel(
    const float* __restrict__ src, bf16* __restrict__ dst, int n)
{
  int i = blockIdx.x * 256 + threadIdx.x;
  if (i < n) dst[i] = __float2bfloat16(src[i]);
}

__global__ __launch_bounds__(256) void embed_kernel(
    const float* __restrict__ src, const float* __restrict__ ew,
    const float* __restrict__ eb, bf16* __restrict__ out)
{
  size_t row = blockIdx.x;
  int i = threadIdx.x;
  out[row * 256 + i] = __float2bfloat16(src[row] * ew[i] + eb[i]);
}

__device__ __forceinline__ float breduce_sum(float v, float* sh) {
  int tid = threadIdx.x;
  sh[tid] = v; __syncthreads();
  for (int s = 128; s > 0; s >>= 1) {
    if (tid < s) sh[tid] += sh[tid + s];
    __syncthreads();
  }
  float r = sh[0]; __syncthreads();
  return r;
}

__global__ __launch_bounds__(256) void stats_kernel(
    const float* __restrict__ src, const float* __restrict__ mask,
    float* __restrict__ stats4)
{
  __shared__ float sh[256];
  const int b = blockIdx.x, t = threadIdx.x;
  const float m = mask[b * 256 + t];
  const float x = src[b * 256 + t] * m;
  float sum = breduce_sum(x, sh);
  float mean = sum * (1.f / 256.f);
  float d = x - mean;
  float var = breduce_sum(d * d, sh) / 255.f;
  float sd = fmaxf(sqrtf(var), 1e-6f);
  float denom = fmaxf(breduce_sum(m, sh), 1e-6f);
  float pk = breduce_sum((x > 1.f + 2.f * sd) ? 1.f : 0.f, sh) / denom;
  float e1 = x - 1.f;
  float sk = (breduce_sum(e1 * e1 * e1 * m, sh) * (1.f / 256.f)) / (sd * sd * sd + 1e-6f);
  float etot = 0.f;
  for (int f = 0; f < 5; ++f) {
    double ang = -2.0 * 3.14159265358979323846 * (double)(f * t) / 256.0;
    float re = breduce_sum(x * (float)cos(ang), sh);
    float im = breduce_sum(x * (float)sin(ang), sh);
    etot += sqrtf(re * re + im * im);
  }
  if (t == 0) {
    stats4[b * 4 + 0] = sd;
    stats4[b * 4 + 1] = pk;
    stats4[b * 4 + 2] = sk;
    stats4[b * 4 + 3] = etot / 5.f;
  }
}

__global__ __launch_bounds__(256) void zmeanmax_kernel(
    const float* __restrict__ z_e, const float* __restrict__ mask,
    float* __restrict__ pooled)
{
  const int b = blockIdx.x, e = threadIdx.x;
  float acc = 0.f, mx = -INFINITY, dsum = 0.f;
  const float* zp = z_e + (size_t)b * SLEN * 256 + e;
  const float* mp = mask + (size_t)b * SLEN;
  for (int t = 0; t < SLEN; ++t) {
    float mt = mp[t];
    float v = zp[(size_t)t * 256] * mt;
    acc += v; mx = fmaxf(mx, v); dsum += mt;
  }
  float denom = fmaxf(dsum, 1e-6f);
  pooled[(size_t)b * 768 + e] = acc / denom;
  pooled[(size_t)b * 768 + 256 + e] = mx;
}

__global__ __launch_bounds__(256) void rowsq_kernel(
    const float* __restrict__ a, float* __restrict__ out)
{
  __shared__ float sh[256];
  const int r = blockIdx.x;
  float v = a[(size_t)r * 256 + threadIdx.x];
  float s = breduce_sum(v * v, sh);
  if (threadIdx.x == 0) out[r] = s;
}

// JAX threefry2x32 (key=(0,42)), partitionable scheme: bits = b1 ^ b2 of
// threefry2x32(key, (0, i)) — verified bit-exact vs dataset (R4/R6 pass).
__device__ __forceinline__ uint2 threefry2x32(uint32_t k0, uint32_t k1,
                                              uint32_t x0, uint32_t x1) {
  uint32_t k2 = k0 ^ k1 ^ 0x1BD11BDAu;
  x0 += k0; x1 += k1;
#define TFR(r) { x0 += x1; x1 = (x1 << r) | (x1 >> (32 - r)); x1 ^= x0; }
  TFR(13) TFR(15) TFR(26) TFR(6)
  x0 += k1; x1 += k2 + 1u;
  TFR(17) TFR(29) TFR(16) TFR(24)
  x0 += k2; x1 += k0 + 2u;
  TFR(13) TFR(15) TFR(26) TFR(6)
  x0 += k0; x1 += k1 + 3u;
  TFR(17) TFR(29) TFR(16) TFR(24)
  x0 += k1; x1 += k2 + 4u;
  TFR(13) TFR(15) TFR(26) TFR(6)
  x0 += k2; x1 += k0 + 5u;
#undef TFR
  return make_uint2(x0, x1);
}

__global__ __launch_bounds__(256) void sample_kernel(
    const float* __restrict__ dots, const float* __restrict__ p2,
    const float* __restrict__ c2, float* __restrict__ out_idx_f,
    int* __restrict__ idx_i)
{
  const int b = blockIdx.x, tid = threadIdx.x;
  const float p2b = p2[b];
  float best = -INFINITY; int bidx = 0;
  for (int k = tid; k < 16384; k += 256) {
    float d2 = fmaxf(p2b + c2[k] - 2.f * dots[(size_t)b * 16384 + k], 0.f);
    float logit = -sqrtf(d2) / 0.7f;
    uint32_t i = (uint32_t)b * 16384u + (uint32_t)k;
    uint2 r = threefry2x32(0u, 42u, 0u, i);
    uint32_t bits = r.x ^ r.y;
    float u = __uint_as_float((bits >> 9) | 0x3f800000u) - 1.0f;
    u = u + 1.17549435e-38f;
    u = fmaxf(u, 1.17549435e-38f);
    float g = -logf(-logf(u));
    float val = logit + g;
    if (val > best) { best = val; bidx = k; }
  }
  __shared__ float bvs[256];
  __shared__ int bks[256];
  bvs[tid] = best; bks[tid] = bidx;
  __syncthreads();
  for (int s = 128; s > 0; s >>= 1) {
    if (tid < s) {
      if (bvs[tid + s] > bvs[tid] ||
          (bvs[tid + s] == bvs[tid] && bks[tid + s] < bks[tid])) {
        bvs[tid] = bvs[tid + s]; bks[tid] = bks[tid + s];
      }
    }
    __syncthreads();
  }
  if (tid == 0) {
    idx_i[b] = bks[0];
    out_idx_f[b] = (float)bks[0];
  }
}

__global__ __launch_bounds__(256) void zqrow_kernel(
    const float* __restrict__ cb, const int* __restrict__ idx,
    float* __restrict__ zqrow)
{
  const int b = blockIdx.x, e = threadIdx.x;
  zqrow[(size_t)b * 256 + e] = cb[(size_t)idx[b] * 256 + e];
}

__global__ __launch_bounds__(256) void zqbcast_kernel(
    const float* __restrict__ zqrow, float* __restrict__ out)
{
  const size_t row = blockIdx.x;
  const int e = threadIdx.x;
  out[row * 256 + e] = zqrow[(row >> 8) * 256 + e];
}

__global__ __launch_bounds__(256) void recon_kernel(
    const bf16* __restrict__ hf, const bf16* __restrict__ hb,
    const float* __restrict__ ow, const float* __restrict__ ob,
    float* __restrict__ out)
{
  const int row = blockIdx.x * 4 + (threadIdx.x >> 6);
  const int lane = threadIdx.x & 63;
  const bf16* pf = hf + (size_t)row * 256;
  const bf16* pb = hb + (size_t)row * 256;
  float s = 0.f;
  for (int i = lane; i < 256; i += 64)
    s += __bfloat162float(pf[i]) * ow[i] + __bfloat162float(pb[i]) * ow[256 + i];
  for (int off = 32; off > 0; off >>= 1) s += __shfl_down(s, off);
  if (lane == 0) out[row] = s + ob[0];
}

// ---------------------------------------------------------------------------
static inline void gemm_bf16(const bf16* A0, const bf16* A1, const bf16* W,
                             const float* bias, const float* rowmask,
                             float* Cf, bf16* Cb, int M, int N, int K,
                             int lda, int ldc, int flags, int rb,
                             hipStream_t s) {
  dim3 g(N / 128, M / 128), b(256);
  int kHalf = A1 ? 256 : K;
  hipLaunchKernelGGL(gemm_bf16_kernel, g, b, 0, s, A0, A1, W, bias, rowmask,
                     Cf, Cb, M, N, K, lda, ldc, flags, rb, kHalf);
}

static inline void gemm(const float* A, const float* W, const float* bias,
                        const float* rowmask, float* C, int M, int N, int K,
                        int lda, int ldw, int ldc, int flags, hipStream_t s) {
  dim3 g(N / TN, M / TM), b(256);
  hipLaunchKernelGGL(gemm_kernel, g, b, 0, s, A, W, bias, rowmask, C,
                     M, N, K, lda, ldw, ldc, flags);
}

// Chunked BiLSTM layer with bf16 activations + swizzled bf16 Whh.
static void bilstm_bf16(const bf16* inF, const bf16* inB, const bf16* Wb,
                        int Kdim, const float* bg, const bf16* w2,
                        const float* pmask, bf16* yf, bf16* yb, float* gates,
                        float* h_g, float* c_g, hipStream_t st) {
  const int M = BATCH * TC;  // 16384
  for (int c = 0; c < SLEN / TC; ++c) {
    int t0f = c * TC;
    int t0b = SLEN - (c + 1) * TC;
    for (int dir = 0; dir < 2; ++dir) {
      int t0 = dir ? t0b : t0f;
      gemm_bf16(inF + (size_t)t0 * 256, inB ? inB + (size_t)t0 * 256 : nullptr,
                Wb + (size_t)dir * NGATE * Kdim, bg + dir * NGATE, nullptr,
                gates + dir * NGATE, nullptr, M, NGATE, Kdim, 256, 2048, 0, 5, st);
    }
    hipLaunchKernelGGL(lstm_kernel, dim3(256), dim3(1024), 0, st,
                       gates, w2, pmask, yf, yb, h_g, c_g,
                       t0f, TC, (c == 0) ? 1 : 0, 2048, TC * 2048);
  }
}

extern "C" void kernel_launch(void* const* d_in, const int* in_sizes, int n_in,
                              void* d_out, int out_size, void* d_ws, size_t ws_size,
                              hipStream_t stream) {
  (void)in_sizes; (void)n_in; (void)out_size;
  const float* src     = (const float*)d_in[0];
  const float* pmask   = (const float*)d_in[1];
  const float* emb_w   = (const float*)d_in[3];
  const float* emb_b   = (const float*)d_in[4];
  const float* e0_Wih  = (const float*)d_in[5];
  const float* e0_Whh  = (const float*)d_in[6];
  const float* e0_b    = (const float*)d_in[7];
  const float* e1_Wih  = (const float*)d_in[8];
  const float* e1_Whh  = (const float*)d_in[9];
  const float* e1_b    = (const float*)d_in[10];
  const float* a_in_w  = (const float*)d_in[11];
  const float* a_in_b  = (const float*)d_in[12];
  const float* a_out_w = (const float*)d_in[13];
  const float* a_out_b = (const float*)d_in[14];
  const float* fc_w    = (const float*)d_in[15];
  const float* fc_b    = (const float*)d_in[16];
  const float* st_w    = (const float*)d_in[17];
  const float* st_b    = (const float*)d_in[18];
  const float* po_w    = (const float*)d_in[19];
  const float* po_b    = (const float*)d_in[20];
  const float* cb      = (const float*)d_in[21];
  const float* dfc_w   = (const float*)d_in[22];
  const float* dfc_b   = (const float*)d_in[23];
  const float* da_in_w = (const float*)d_in[24];
  const float* da_in_b = (const float*)d_in[25];
  const float* da_out_w= (const float*)d_in[26];
  const float* da_out_b= (const float*)d_in[27];
  const float* d0_Wih  = (const float*)d_in[28];
  const float* d0_Whh  = (const float*)d_in[29];
  const float* d0_b    = (const float*)d_in[30];
  const float* d1_Wih  = (const float*)d_in[31];
  const float* d1_Whh  = (const float*)d_in[32];
  const float* d1_b    = (const float*)d_in[33];
  const float* out_w   = (const float*)d_in[34];
  const float* out_b   = (const float*)d_in[35];

  float* out = (float*)d_out;
  float* ws  = (float*)d_ws;

  // ---- workspace layout (float units): ~309 MB ----
  float* S3   = ws;                                    // 33,554,432
  bf16*  S1b  = (bf16*)(ws + 33554432);                // 16,777,216 f
  bf16*  S2b  = (bf16*)(ws + 33554432 + 16777216);     // 16,777,216 f
  bf16*  Xb   = (bf16*)(ws + 33554432 + 2 * 16777216);         // 4,194,304 f
  bf16*  WbB  = (bf16*)(ws + 33554432 + 2 * 16777216 + 4194304); // 1,900,544 f
  bf16*  Whh2 = (bf16*)(ws + 73203712);                // 1,048,576 f (4x524288 bf16)
  float* SM   = ws + 74252288;
  float* h_state = SM;
  float* c_state = SM + 262144;
  float* pooled  = SM + 524288;
  float* phrase  = SM + 917504;
  float* stats4  = SM + 1048576;
  float* p2      = SM + 1050624;
  float* c2      = SM + 1051136;
  int*   idx_i   = (int*)(SM + 1067520);
  float* zqrow   = SM + 1068032;
  float* hd      = SM + 1199104;
  float* vb      = SM + 1461248;
  float* dab     = SM + 1723392;
  float* xwdec   = SM + 1985536;
  const size_t NEED_BYTES = (74252288ull + 3034112) * 4;
  if (ws_size < NEED_BYTES) return;

  // bf16 weight sub-buffers (Wih etc., plain row-major)
  bf16* e0Wb  = WbB;                 // 2*1024*256
  bf16* e1Wb  = WbB + 524288;        // 2*1024*512
  bf16* ainWb = WbB + 1572864;       // 1536*512
  bf16* aoutWb= WbB + 2359296;       // 512*512
  bf16* fcWb  = WbB + 2621440;       // 256*512
  bf16* d1Wb  = WbB + 2752512;       // 2*1024*512
  // swizzled bf16 Whh
  bf16* e0W2 = Whh2;
  bf16* e1W2 = Whh2 + 524288;
  bf16* d0W2 = Whh2 + 1048576;
  bf16* d1W2 = Whh2 + 1572864;

  float* o_recon = out;
  float* o_ze    = out + 131072;
  float* o_zq    = out + 33685504;
  float* o_idx   = out + 67239936;
  bf16*  Eb     = (bf16*)o_ze;       // embed scratch (dead after e0 GEMMs)
  bf16*  ctxf_b = (bf16*)o_zq;       // ctx halves in o_zq region (R6 layout)
  bf16*  ctxb_b = (bf16*)o_zq + 33554432;

  const int BS = BATCH * SLEN;

  // ---- weight conversions ----
  hipLaunchKernelGGL(f2b_kernel, dim3(2048), dim3(256), 0, stream, e0_Wih, e0Wb, 524288);
  hipLaunchKernelGGL(f2b_kernel, dim3(4096), dim3(256), 0, stream, e1_Wih, e1Wb, 1048576);
  hipLaunchKernelGGL(f2b_kernel, dim3(3072), dim3(256), 0, stream, a_in_w, ainWb, 786432);
  hipLaunchKernelGGL(f2b_kernel, dim3(1024), dim3(256), 0, stream, a_out_w, aoutWb, 262144);
  hipLaunchKernelGGL(f2b_kernel, dim3(512),  dim3(256), 0, stream, fc_w, fcWb, 131072);
  hipLaunchKernelGGL(f2b_kernel, dim3(4096), dim3(256), 0, stream, d1_Wih, d1Wb, 1048576);
  hipLaunchKernelGGL(whh2b_kernel, dim3(2048), dim3(256), 0, stream, e0_Whh, e0W2);
  hipLaunchKernelGGL(whh2b_kernel, dim3(2048), dim3(256), 0, stream, e1_Whh, e1W2);
  hipLaunchKernelGGL(whh2b_kernel, dim3(2048), dim3(256), 0, stream, d0_Whh, d0W2);
  hipLaunchKernelGGL(whh2b_kernel, dim3(2048), dim3(256), 0, stream, d1_Whh, d1W2);

  // ---- encoder ----
  hipLaunchKernelGGL(embed_kernel, dim3(BS), dim3(256), 0, stream,
                     src, emb_w, emb_b, Eb);
  bilstm_bf16(Eb, nullptr, e0Wb, 256, e0_b, e0W2, pmask,
              S1b, S2b, S3, h_state, c_state, stream);
  bilstm_bf16(S1b, S2b, e1Wb, 512, e1_b, e1W2, pmask,
              S1b, S2b, S3, h_state, c_state, stream);   // in-place

  // attention, batch-chunked: QKV (fp32) into S3, ctx (bf16) into o_zq region
  for (int b0 = 0; b0 < BATCH; b0 += BC) {
    gemm_bf16(S1b + (size_t)b0 * SLEN * 256, S2b + (size_t)b0 * SLEN * 256,
              ainWb, a_in_b, nullptr, S3, nullptr,
              BC * SLEN, 1536, 512, 256, 1536, 0, -1, stream);
    hipLaunchKernelGGL(attn_kernel, dim3(8, BC), dim3(256), 0, stream,
                       S3, pmask, ctxf_b, ctxb_b, b0);
  }
  // attn-out (bf16 out) then z_e (fp32 out), batch-chunked
  for (int b0 = 0; b0 < BATCH; b0 += BC) {
    gemm_bf16(ctxf_b + (size_t)b0 * SLEN * 256, ctxb_b + (size_t)b0 * SLEN * 256,
              aoutWb, a_out_b, pmask + (size_t)b0 * SLEN, nullptr, Xb,
              BC * SLEN, 512, 512, 256, 512, GF_ROWMASK, -1, stream);
    gemm_bf16(Xb, nullptr, fcWb, fc_b, nullptr,
              o_ze + (size_t)b0 * SLEN * 256, nullptr,
              BC * SLEN, 256, 512, 512, 256, 0, -1, stream);
  }

  // ---- pooling / stats / phrase ----
  hipLaunchKernelGGL(zmeanmax_kernel, dim3(512), dim3(256), 0, stream,
                     o_ze, pmask, pooled);
  hipLaunchKernelGGL(stats_kernel, dim3(512), dim3(256), 0, stream,
                     src, pmask, stats4);
  gemm(stats4, st_w, st_b, nullptr, pooled + 512, 512, 256, 4,
       4, 4, 768, 0, stream);
  gemm(pooled, po_w, po_b, nullptr, phrase, 512, 256, 768,
       768, 768, 256, 0, stream);

  // ---- VQ: fp32 distances + exact JAX categorical sampling ----
  hipLaunchKernelGGL(rowsq_kernel, dim3(512), dim3(256), 0, stream, phrase, p2);
  hipLaunchKernelGGL(rowsq_kernel, dim3(16384), dim3(256), 0, stream, cb, c2);
  gemm(phrase, cb, nullptr, nullptr, S3, 512, 16384, 256,
       256, 256, 16384, 0, stream);
  hipLaunchKernelGGL(sample_kernel, dim3(512), dim3(256), 0, stream,
                     S3, p2, c2, o_idx, idx_i);
  hipLaunchKernelGGL(zqrow_kernel, dim3(512), dim3(256), 0, stream,
                     cb, idx_i, zqrow);
  hipLaunchKernelGGL(zqbcast_kernel, dim3(BS), dim3(256), 0, stream,
                     zqrow, o_zq);

  // ---- decoder prelude (fp32 naive, tiny): fc -> collapsed MHA -> xW ----
  gemm(zqrow, dfc_w, dfc_b, nullptr, hd, 512, 512, 256,
       256, 256, 512, GF_RELU, stream);
  gemm(hd, da_in_w + (size_t)1024 * 512, da_in_b + 1024, nullptr, vb,
       512, 512, 512, 512, 512, 512, 0, stream);
  gemm(vb, da_out_w, da_out_b, nullptr, dab, 512, 512, 512,
       512, 512, 512, 0, stream);
  gemm(dab, d0_Wih, d0_b, nullptr, xwdec, 512, 2048, 512,
       512, 512, 2048, 0, stream);

  // ---- decoder LSTMs + output projection ----
  hipLaunchKernelGGL(lstm_kernel, dim3(256), dim3(1024), 0, stream,
                     xwdec, d0W2, pmask, S1b, S2b, h_state, c_state,
                     0, SLEN, 1, 0, 2048);
  bilstm_bf16(S1b, S2b, d1Wb, 512, d1_b, d1W2, pmask,
              S1b, S2b, S3, h_state, c_state, stream);   // in-place
  hipLaunchKernelGGL(recon_kernel, dim3(BS / 4), dim3(256), 0, stream,
                     S1b, S2b, out_w, out_b, o_recon);
}